// Round 15
// baseline (404.145 us; speedup 1.0000x reference)
//
#include <hip/hip_runtime.h>

#define F 64      // F_IN == HID
#define EF 32
#define COUT 4

typedef unsigned int uint;
typedef unsigned short ushort;
typedef __attribute__((ext_vector_type(8))) short bf16x8;
typedef __attribute__((ext_vector_type(4))) float f32x4;

__device__ inline ushort f2bf(float f) {           // RNE float->bf16
    uint u = __float_as_uint(f);
    return (ushort)((u + 0x7fff + ((u >> 16) & 1)) >> 16);
}
__device__ inline float bf2f(ushort u) {
    return __uint_as_float(((uint)u) << 16);
}
__device__ inline float blo(uint u) { return __uint_as_float(u << 16); }
__device__ inline float bhi(uint u) { return __uint_as_float(u & 0xffff0000u); }
__device__ inline int swzb(int b) { return b ^ (((b >> 6) & 3) << 4); }  // LDS bank swizzle

// ---------------------------------------------------------------- kernels

__global__ void k_deg(const int* __restrict__ dst, int* __restrict__ deg, int E) {
    int i = blockIdx.x * blockDim.x + threadIdx.x;
    if (i < E) atomicAdd(&deg[dst[i]], 1);
}

__global__ void k_dinv(const int* __restrict__ deg, float* __restrict__ dinv, int n) {
    int i = blockIdx.x * blockDim.x + threadIdx.x;
    if (i < n) dinv[i] = rsqrtf((float)(deg[i] + 1));
}

__global__ void k_xcast(const float* __restrict__ x, ushort* __restrict__ xb, int n4) {
    int i = blockIdx.x * 256 + threadIdx.x;
    if (i >= n4) return;
    f32x4 v = __builtin_nontemporal_load((const f32x4*)(x + (size_t)i * 4));
    ushort4 o;
    o.x = f2bf(v.x); o.y = f2bf(v.y); o.z = f2bf(v.z); o.w = f2bf(v.w);
    *(ushort4*)(xb + (size_t)i * 4) = o;
}

// ---- exclusive scan of deg -> rowptr ----

__global__ void k_blocksum(const int* __restrict__ deg, int* __restrict__ bsum, int n) {
    __shared__ int sm[256];
    int i = blockIdx.x * 256 + threadIdx.x;
    sm[threadIdx.x] = (i < n) ? deg[i] : 0;
    __syncthreads();
    for (int s = 128; s > 0; s >>= 1) {
        if (threadIdx.x < s) sm[threadIdx.x] += sm[threadIdx.x + s];
        __syncthreads();
    }
    if (threadIdx.x == 0) bsum[blockIdx.x] = sm[0];
}

__global__ void k_scanb(const int* __restrict__ bsum, int* __restrict__ boffs, int nb) {
    int lane = threadIdx.x;
    int carry = 0;
    for (int base = 0; base < nb; base += 64) {
        int v = (base + lane < nb) ? bsum[base + lane] : 0;
        int incl = v;
        #pragma unroll
        for (int off = 1; off < 64; off <<= 1) {
            int t = __shfl_up(incl, off);
            if (lane >= off) incl += t;
        }
        if (base + lane < nb) boffs[base + lane] = carry + incl - v;
        carry += __shfl(incl, 63);
    }
}

__global__ void k_rowptr(const int* __restrict__ deg, const int* __restrict__ boffs,
                         int* __restrict__ rowptr, int n) {
    __shared__ int sm[256];
    int tid = threadIdx.x;
    int i = blockIdx.x * 256 + tid;
    int v = (i < n) ? deg[i] : 0;
    sm[tid] = v;
    __syncthreads();
    for (int off = 1; off < 256; off <<= 1) {
        int t = (tid >= off) ? sm[tid - off] : 0;
        __syncthreads();
        sm[tid] += t;
        __syncthreads();
    }
    if (i < n) rowptr[i] = boffs[blockIdx.x] + sm[tid] - v;
}

// bucket entries: es2[pos] = (src, bitcast(dinv[src]))
__global__ void k_bucket(const int* __restrict__ src, const int* __restrict__ dst,
                         const float* __restrict__ dinv,
                         const int* __restrict__ rowptr, int* __restrict__ fill,
                         int2* __restrict__ es2, int E) {
    int e = blockIdx.x * 256 + threadIdx.x;
    if (e >= E) return;
    int d = dst[e], s = src[e];
    int pos = rowptr[d] + atomicAdd(&fill[d], 1);
    es2[pos] = make_int2(s, __float_as_int(dinv[s]));
}

// gather-aggregate: one wave per node; lane=(slot 0..7 edges, oct 0..7 bf16-octets)
__global__ __launch_bounds__(256) void k_agg(
    const ushort* __restrict__ xb, const float* __restrict__ dinv,
    const int2* __restrict__ es2, const int* __restrict__ rowptr,
    const int* __restrict__ deg, ushort* __restrict__ xaggb, int n) {
    int node = (blockIdx.x * 256 + threadIdx.x) >> 6;
    int lane = threadIdx.x & 63;
    if (node >= n) return;
    int slot = lane >> 3, oct = lane & 7;
    int start = rowptr[node], cnt = deg[node];
    float di = dinv[node];
    float a0 = 0.f, a1 = 0.f, a2 = 0.f, a3 = 0.f, a4 = 0.f, a5 = 0.f, a6 = 0.f, a7 = 0.f;
    for (int base = 0; base < cnt; base += 16) {
        int k0 = base + slot, k1 = base + slot + 8;
        bool v0 = k0 < cnt, v1 = k1 < cnt;
        int2 e0 = make_int2(0, 0), e1 = make_int2(0, 0);
        if (v0) e0 = es2[start + k0];
        if (v1) e1 = es2[start + k1];
        uint4 r0 = make_uint4(0u, 0u, 0u, 0u), r1 = make_uint4(0u, 0u, 0u, 0u);
        if (v0) r0 = *(const uint4*)(xb + (size_t)e0.x * F + oct * 8);
        if (v1) r1 = *(const uint4*)(xb + (size_t)e1.x * F + oct * 8);
        float w0 = v0 ? __int_as_float(e0.y) * di : 0.f;
        float w1 = v1 ? __int_as_float(e1.y) * di : 0.f;
        a0 += w0 * blo(r0.x) + w1 * blo(r1.x);
        a1 += w0 * bhi(r0.x) + w1 * bhi(r1.x);
        a2 += w0 * blo(r0.y) + w1 * blo(r1.y);
        a3 += w0 * bhi(r0.y) + w1 * bhi(r1.y);
        a4 += w0 * blo(r0.z) + w1 * blo(r1.z);
        a5 += w0 * bhi(r0.z) + w1 * bhi(r1.z);
        a6 += w0 * blo(r0.w) + w1 * blo(r1.w);
        a7 += w0 * bhi(r0.w) + w1 * bhi(r1.w);
    }
    a0 += __shfl_xor(a0, 8); a0 += __shfl_xor(a0, 16); a0 += __shfl_xor(a0, 32);
    a1 += __shfl_xor(a1, 8); a1 += __shfl_xor(a1, 16); a1 += __shfl_xor(a1, 32);
    a2 += __shfl_xor(a2, 8); a2 += __shfl_xor(a2, 16); a2 += __shfl_xor(a2, 32);
    a3 += __shfl_xor(a3, 8); a3 += __shfl_xor(a3, 16); a3 += __shfl_xor(a3, 32);
    a4 += __shfl_xor(a4, 8); a4 += __shfl_xor(a4, 16); a4 += __shfl_xor(a4, 32);
    a5 += __shfl_xor(a5, 8); a5 += __shfl_xor(a5, 16); a5 += __shfl_xor(a5, 32);
    a6 += __shfl_xor(a6, 8); a6 += __shfl_xor(a6, 16); a6 += __shfl_xor(a6, 32);
    a7 += __shfl_xor(a7, 8); a7 += __shfl_xor(a7, 16); a7 += __shfl_xor(a7, 32);
    if (slot == 0) {
        float dd = di * di;
        uint4 xv = *(const uint4*)(xb + (size_t)node * F + oct * 8);
        a0 += dd * blo(xv.x); a1 += dd * bhi(xv.x);
        a2 += dd * blo(xv.y); a3 += dd * bhi(xv.y);
        a4 += dd * blo(xv.z); a5 += dd * bhi(xv.z);
        a6 += dd * blo(xv.w); a7 += dd * bhi(xv.w);
        uint4 o;
        o.x = (uint)f2bf(a0) | ((uint)f2bf(a1) << 16);
        o.y = (uint)f2bf(a2) | ((uint)f2bf(a3) << 16);
        o.z = (uint)f2bf(a4) | ((uint)f2bf(a5) << 16);
        o.w = (uint)f2bf(a6) | ((uint)f2bf(a7) << 16);
        *(uint4*)(xaggb + (size_t)node * F + oct * 8) = o;
    }
}

// B1t[c][k] (bf16): c<64 -> Mz[k][c]; c>=64 -> Mh[k][c-64]. V = biases.
__global__ void k_weights(const float* __restrict__ Wz, const float* __restrict__ bz,
                          const float* __restrict__ Wh, const float* __restrict__ bh,
                          const float* __restrict__ Wlz, const float* __restrict__ blz,
                          const float* __restrict__ Wlh, const float* __restrict__ blh,
                          ushort* __restrict__ B1t, float* __restrict__ V) {
    int j = threadIdx.x;
    int k = blockIdx.x;
    if (k < 64) {
        float sz = 0.f, sh = 0.f;
        for (int i = 0; i < 64; ++i) {
            sz += Wz[k * 64 + i] * Wlz[i * 64 + j];
            sh += Wh[k * 64 + i] * Wlh[i * 64 + j];
        }
        B1t[j * 64 + k]        = f2bf(sz);
        B1t[(64 + j) * 64 + k] = f2bf(sh);
    } else {
        float sz = blz[j], sh = blh[j];
        for (int i = 0; i < 64; ++i) {
            sz += bz[i] * Wlz[i * 64 + j];
            sh += bh[i] * Wlh[i * 64 + j];
        }
        V[j]      = sz;
        V[64 + j] = sh;
    }
}

// B2t[c][k] (bf16): c<64 -> W1a[k][c]; c>=64 -> W1b[k][c-64]
// W1cTb[j][k] (bf16, [64][32]): = W1c[k][j] = W1[128+k][j]
__global__ void k_wcast(const float* __restrict__ W1, ushort* __restrict__ B2t,
                        ushort* __restrict__ W1cTb) {
    int i = blockIdx.x * 256 + threadIdx.x;
    if (i < 8192) {
        int c = i >> 6, k = i & 63;
        int row = (c < 64) ? k : (64 + k);
        B2t[i] = f2bf(W1[row * 64 + (c & 63)]);
    }
    int t = i - 8192;
    if (t >= 0 && t < 2048) {
        int j = t >> 5, k = t & 31;
        W1cTb[t] = f2bf(W1[(128 + k) * 64 + j]);
    }
}

// MFMA node kernel (unchanged from R5)
__global__ __launch_bounds__(256) void k_node(
    const ushort* __restrict__ xaggb, const ushort* __restrict__ B1t,
    const ushort* __restrict__ B2t, const float* __restrict__ V,
    const float* __restrict__ b1,
    ushort* __restrict__ Pb, ushort* __restrict__ Qb, int n) {
    __shared__ ushort hsm[64 * 64];
    int wid = threadIdx.x >> 6, lane = threadIdx.x & 63;
    int lg = lane >> 4, lc = lane & 15;
    int base = blockIdx.x * 64;

    bf16x8 b1f[2][2], b2f[2][2];
    #pragma unroll
    for (int t = 0; t < 2; ++t) {
        int c1 = ((t ? wid + 4 : wid) * 16 + lc) * 64;
        int c2 = ((wid * 2 + t) * 16 + lc) * 64;
        #pragma unroll
        for (int ks = 0; ks < 2; ++ks) {
            b1f[t][ks] = *(const bf16x8*)(B1t + c1 + ks * 32 + lg * 8);
            b2f[t][ks] = *(const bf16x8*)(B2t + c2 + ks * 32 + lg * 8);
        }
    }
    float vzc = V[wid * 16 + lc], vhc = V[64 + wid * 16 + lc];
    float bP[2];
    #pragma unroll
    for (int t = 0; t < 2; ++t) {
        int c2 = (wid * 2 + t) * 16 + lc;
        bP[t] = (c2 < 64) ? b1[c2] : 0.f;
    }

    const f32x4 fz = {0.f, 0.f, 0.f, 0.f};
    f32x4 accZ[4], accT[4];
    #pragma unroll
    for (int rt = 0; rt < 4; ++rt) { accZ[rt] = fz; accT[rt] = fz; }

    #pragma unroll
    for (int rt = 0; rt < 4; ++rt) {
        const ushort* ap = xaggb + (size_t)(base + rt * 16 + lc) * 64 + lg * 8;
        bf16x8 a0 = *(const bf16x8*)(ap);
        bf16x8 a1 = *(const bf16x8*)(ap + 32);
        accZ[rt] = __builtin_amdgcn_mfma_f32_16x16x32_bf16(a0, b1f[0][0], accZ[rt], 0, 0, 0);
        accZ[rt] = __builtin_amdgcn_mfma_f32_16x16x32_bf16(a1, b1f[0][1], accZ[rt], 0, 0, 0);
        accT[rt] = __builtin_amdgcn_mfma_f32_16x16x32_bf16(a0, b1f[1][0], accT[rt], 0, 0, 0);
        accT[rt] = __builtin_amdgcn_mfma_f32_16x16x32_bf16(a1, b1f[1][1], accT[rt], 0, 0, 0);
    }

    #pragma unroll
    for (int rt = 0; rt < 4; ++rt) {
        #pragma unroll
        for (int r = 0; r < 4; ++r) {
            float z = 1.f / (1.f + __expf(-(accZ[rt][r] + vzc)));
            float tt = tanhf(accT[rt][r] + vhc);
            float h = (1.f - z) * tt;
            int row = rt * 16 + lg * 4 + r;
            int byte = ((row * 64 + wid * 16 + lc) * 2) ^ ((row & 7) << 4);
            *(ushort*)((char*)hsm + byte) = f2bf(h);
        }
    }
    __syncthreads();

    f32x4 acc2[2][4];
    #pragma unroll
    for (int rt = 0; rt < 4; ++rt) { acc2[0][rt] = fz; acc2[1][rt] = fz; }
    #pragma unroll
    for (int rt = 0; rt < 4; ++rt) {
        #pragma unroll
        for (int ks = 0; ks < 2; ++ks) {
            int row = rt * 16 + lc;
            int byte = (row * 128 + ks * 64 + lg * 16) ^ ((row & 7) << 4);
            bf16x8 a2 = *(const bf16x8*)((char*)hsm + byte);
            acc2[0][rt] = __builtin_amdgcn_mfma_f32_16x16x32_bf16(a2, b2f[0][ks], acc2[0][rt], 0, 0, 0);
            acc2[1][rt] = __builtin_amdgcn_mfma_f32_16x16x32_bf16(a2, b2f[1][ks], acc2[1][rt], 0, 0, 0);
        }
    }

    ushort* dstb = (wid < 2) ? Pb : Qb;
    #pragma unroll
    for (int t = 0; t < 2; ++t) {
        int cl = ((wid * 2 + t) * 16 + lc) & 63;
        #pragma unroll
        for (int rt = 0; rt < 4; ++rt) {
            #pragma unroll
            for (int r = 0; r < 4; ++r) {
                int node = base + rt * 16 + lg * 4 + r;
                if (node < n) dstb[(size_t)node * 64 + cl] = f2bf(acc2[t][rt][r] + bP[t]);
            }
        }
    }
}

// Fused MFMA edge kernel, original order + nt streaming + 8-wave occupancy:
// W1cT and W2 served from LDS; launch_bounds caps VGPR at 64.
__global__ __launch_bounds__(256, 8) void k_edge2(
    const int* __restrict__ src, const int* __restrict__ dst,
    const float* __restrict__ attr,
    const ushort* __restrict__ Pb, const ushort* __restrict__ Qb,
    const ushort* __restrict__ W1cTb,
    const float* __restrict__ W2, const float* __restrict__ b2,
    float* __restrict__ out, int E) {
    __shared__ float w2s[256];
    __shared__ float b2s[4];
    __shared__ ushort wts[2048 + 64];   // W1cT, XOR-swizzled (4 KB + pad)
    w2s[threadIdx.x] = W2[threadIdx.x];
    if (threadIdx.x < 4) b2s[threadIdx.x] = b2[threadIdx.x];
    #pragma unroll
    for (int t = 0; t < 8; ++t) {
        int i = t * 256 + threadIdx.x;   // ushort index 0..2047
        int b = swzb(i * 2);
        *(ushort*)((char*)wts + b) = W1cTb[i];
    }
    __syncthreads();

    int wid = threadIdx.x >> 6, lane = threadIdx.x & 63;
    int lg = lane >> 4, lc = lane & 15;
    int we = (blockIdx.x * 4 + wid) * 64;
    if (we >= E) return;

    int idx = we + lane; if (idx >= E) idx = E - 1;
    int sR = __builtin_nontemporal_load(src + idx);
    int dR = __builtin_nontemporal_load(dst + idx);

    const f32x4 fz = {0.f, 0.f, 0.f, 0.f};
    #pragma unroll
    for (int et = 0; et < 4; ++et) {
        int erow = et * 16 + lc;
        int eid_e = we + erow; if (eid_e >= E) eid_e = E - 1;
        int s_e = __shfl(sR, erow);
        int d_e = __shfl(dR, erow);

        // B-frag: attr[eid_e][lg*8 .. +7] -> bf16 (coalesced, non-temporal)
        const f32x4* ap = (const f32x4*)(attr + (size_t)eid_e * EF + lg * 8);
        f32x4 a0 = __builtin_nontemporal_load(ap);
        f32x4 a1 = __builtin_nontemporal_load(ap + 1);
        bf16x8 bfr;
        bfr[0] = (short)f2bf(a0.x); bfr[1] = (short)f2bf(a0.y);
        bfr[2] = (short)f2bf(a0.z); bfr[3] = (short)f2bf(a0.w);
        bfr[4] = (short)f2bf(a1.x); bfr[5] = (short)f2bf(a1.y);
        bfr[6] = (short)f2bf(a1.z); bfr[7] = (short)f2bf(a1.w);

        f32x4 acc[4];
        #pragma unroll
        for (int rt = 0; rt < 4; ++rt) acc[rt] = fz;
        #pragma unroll
        for (int rt = 0; rt < 4; ++rt) {
            int b = swzb(((rt * 16 + lc) * 32 + lg * 8) * 2);
            bf16x8 aW = *(const bf16x8*)((char*)wts + b);
            acc[rt] = __builtin_amdgcn_mfma_f32_16x16x32_bf16(aW, bfr, acc[rt], 0, 0, 0);
        }

        const ushort* Ps = Pb + (size_t)s_e * F;
        const ushort* Qd = Qb + (size_t)d_e * F;
        float o0 = 0.f, o1 = 0.f, o2 = 0.f, o3 = 0.f;
        #pragma unroll
        for (int rt = 0; rt < 4; ++rt) {
            int j0 = rt * 16 + lg * 4;
            uint2 pv = *(const uint2*)(Ps + j0);
            uint2 qv = *(const uint2*)(Qd + j0);
            float p0 = blo(pv.x), p1 = bhi(pv.x), p2 = blo(pv.y), p3 = bhi(pv.y);
            float q0 = blo(qv.x), q1 = bhi(qv.x), q2 = blo(qv.y), q3 = bhi(qv.y);
            float h0 = fmaxf(acc[rt][0] + p0 + q0, 0.f);
            float h1 = fmaxf(acc[rt][1] + p1 + q1, 0.f);
            float h2 = fmaxf(acc[rt][2] + p2 + q2, 0.f);
            float h3 = fmaxf(acc[rt][3] + p3 + q3, 0.f);
            float4 w0 = *(const float4*)(&w2s[(j0 + 0) * 4]);
            float4 w1 = *(const float4*)(&w2s[(j0 + 1) * 4]);
            float4 w2v = *(const float4*)(&w2s[(j0 + 2) * 4]);
            float4 w3 = *(const float4*)(&w2s[(j0 + 3) * 4]);
            o0 += h0 * w0.x + h1 * w1.x + h2 * w2v.x + h3 * w3.x;
            o1 += h0 * w0.y + h1 * w1.y + h2 * w2v.y + h3 * w3.y;
            o2 += h0 * w0.z + h1 * w1.z + h2 * w2v.z + h3 * w3.z;
            o3 += h0 * w0.w + h1 * w1.w + h2 * w2v.w + h3 * w3.w;
        }
        o0 += __shfl_xor(o0, 16); o0 += __shfl_xor(o0, 32);
        o1 += __shfl_xor(o1, 16); o1 += __shfl_xor(o1, 32);
        o2 += __shfl_xor(o2, 16); o2 += __shfl_xor(o2, 32);
        o3 += __shfl_xor(o3, 16); o3 += __shfl_xor(o3, 32);
        if (lg == 0 && (we + erow) < E) {
            f32x4 ov = {o0 + b2s[0], o1 + b2s[1], o2 + b2s[2], o3 + b2s[3]};
            __builtin_nontemporal_store(ov, (f32x4*)(out + (size_t)(we + erow) * 4));
        }
    }
}

// ---------------------------------------------------------------- launch

extern "C" void kernel_launch(void* const* d_in, const int* in_sizes, int n_in,
                              void* d_out, int out_size, void* d_ws, size_t ws_size,
                              hipStream_t stream) {
    const float* x    = (const float*)d_in[0];
    const int*   ei   = (const int*)d_in[1];
    const float* attr = (const float*)d_in[2];
    const float* Wz   = (const float*)d_in[3];
    const float* bz   = (const float*)d_in[4];
    const float* Wh   = (const float*)d_in[7];
    const float* bh   = (const float*)d_in[8];
    const float* Wlz  = (const float*)d_in[9];
    const float* blz  = (const float*)d_in[10];
    const float* Wlh  = (const float*)d_in[13];
    const float* blh  = (const float*)d_in[14];
    const float* W1   = (const float*)d_in[15];
    const float* b1   = (const float*)d_in[16];
    const float* W2   = (const float*)d_in[17];
    const float* b2   = (const float*)d_in[18];
    float* out = (float*)d_out;

    const int N = in_sizes[0] / F;
    const int E = in_sizes[1] / 2;
    const int* src = ei;
    const int* dst = ei + E;
    const int NB = (N + 255) / 256;
    const int NBT = (N + 63) / 64;

    // workspace layout; xb dead after k_agg -> Pb aliases it
    ushort* xaggb = (ushort*)d_ws;                      // N*F ushort
    ushort* regB  = xaggb + (size_t)N * F;              // N*F ushort: xb then Pb
    ushort* Qb    = regB + (size_t)N * F;               // N*F ushort
    ushort* B1t   = Qb + (size_t)N * F;                 // 8192
    ushort* B2t   = B1t + 8192;                         // 8192
    ushort* W1cTb = B2t + 8192;                         // 2048
    float*  V     = (float*)(W1cTb + 2048);             // 128
    int2*   es2   = (int2*)(V + 128);                   // E int2
    int*    deg   = (int*)(es2 + (size_t)E);            // N
    float*  dinv  = (float*)(deg + N);                  // N
    int*    rowptr= (int*)(dinv + N);                   // N
    int*    fill  = rowptr + N;                         // N
    int*    bsum  = fill + N;                           // <=512
    int*    boffs = bsum + 512;                         // <=512
    ushort* xb = regB;
    ushort* Pb = regB;

    hipMemsetAsync(deg, 0, (size_t)N * sizeof(int), stream);
    hipMemsetAsync(fill, 0, (size_t)N * sizeof(int), stream);

    k_deg<<<(E + 255) / 256, 256, 0, stream>>>(dst, deg, E);
    k_dinv<<<NB, 256, 0, stream>>>(deg, dinv, N);
    k_weights<<<65, 64, 0, stream>>>(Wz, bz, Wh, bh, Wlz, blz, Wlh, blh, B1t, V);
    k_wcast<<<40, 256, 0, stream>>>(W1, B2t, W1cTb);
    k_xcast<<<(N * F / 4 + 255) / 256, 256, 0, stream>>>(x, xb, N * F / 4);

    // CSR build
    k_blocksum<<<NB, 256, 0, stream>>>(deg, bsum, N);
    k_scanb<<<1, 64, 0, stream>>>(bsum, boffs, NB);
    k_rowptr<<<NB, 256, 0, stream>>>(deg, boffs, rowptr, N);
    k_bucket<<<(E + 255) / 256, 256, 0, stream>>>(src, dst, dinv, rowptr, fill, es2, E);

    k_agg<<<(N * 64 + 255) / 256, 256, 0, stream>>>(xb, dinv, es2, rowptr, deg, xaggb, N);

    k_node<<<NBT, 256, 0, stream>>>(xaggb, B1t, B2t, V, b1, Pb, Qb, N);

    k_edge2<<<(E + 255) / 256, 256, 0, stream>>>(src, dst, attr, Pb, Qb, W1cTb, W2, b2, out, E);
}

// Round 16
// 388.884 us; speedup vs baseline: 1.0392x; 1.0392x over previous
//
#include <hip/hip_runtime.h>

#define F 64      // F_IN == HID
#define EF 32
#define COUT 4

typedef unsigned int uint;
typedef unsigned short ushort;
typedef __attribute__((ext_vector_type(8))) short bf16x8;
typedef __attribute__((ext_vector_type(4))) float f32x4;

__device__ inline ushort f2bf(float f) {           // RNE float->bf16
    uint u = __float_as_uint(f);
    return (ushort)((u + 0x7fff + ((u >> 16) & 1)) >> 16);
}
__device__ inline float bf2f(ushort u) {
    return __uint_as_float(((uint)u) << 16);
}
__device__ inline float blo(uint u) { return __uint_as_float(u << 16); }
__device__ inline float bhi(uint u) { return __uint_as_float(u & 0xffff0000u); }

// ---------------------------------------------------------------- kernels

__global__ void k_deg(const int* __restrict__ dst, int* __restrict__ deg, int E) {
    int i = blockIdx.x * blockDim.x + threadIdx.x;
    if (i < E) atomicAdd(&deg[dst[i]], 1);
}

__global__ void k_dinv(const int* __restrict__ deg, float* __restrict__ dinv, int n) {
    int i = blockIdx.x * blockDim.x + threadIdx.x;
    if (i < n) dinv[i] = rsqrtf((float)(deg[i] + 1));
}

__global__ void k_xcast(const float* __restrict__ x, ushort* __restrict__ xb, int n4) {
    int i = blockIdx.x * 256 + threadIdx.x;
    if (i >= n4) return;
    f32x4 v = __builtin_nontemporal_load((const f32x4*)(x + (size_t)i * 4));
    ushort4 o;
    o.x = f2bf(v.x); o.y = f2bf(v.y); o.z = f2bf(v.z); o.w = f2bf(v.w);
    *(ushort4*)(xb + (size_t)i * 4) = o;
}

// ---- exclusive scan of deg -> rowptr ----

__global__ void k_blocksum(const int* __restrict__ deg, int* __restrict__ bsum, int n) {
    __shared__ int sm[256];
    int i = blockIdx.x * 256 + threadIdx.x;
    sm[threadIdx.x] = (i < n) ? deg[i] : 0;
    __syncthreads();
    for (int s = 128; s > 0; s >>= 1) {
        if (threadIdx.x < s) sm[threadIdx.x] += sm[threadIdx.x + s];
        __syncthreads();
    }
    if (threadIdx.x == 0) bsum[blockIdx.x] = sm[0];
}

__global__ void k_scanb(const int* __restrict__ bsum, int* __restrict__ boffs, int nb) {
    int lane = threadIdx.x;
    int carry = 0;
    for (int base = 0; base < nb; base += 64) {
        int v = (base + lane < nb) ? bsum[base + lane] : 0;
        int incl = v;
        #pragma unroll
        for (int off = 1; off < 64; off <<= 1) {
            int t = __shfl_up(incl, off);
            if (lane >= off) incl += t;
        }
        if (base + lane < nb) boffs[base + lane] = carry + incl - v;
        carry += __shfl(incl, 63);
    }
}

__global__ void k_rowptr(const int* __restrict__ deg, const int* __restrict__ boffs,
                         int* __restrict__ rowptr, int n) {
    __shared__ int sm[256];
    int tid = threadIdx.x;
    int i = blockIdx.x * 256 + tid;
    int v = (i < n) ? deg[i] : 0;
    sm[tid] = v;
    __syncthreads();
    for (int off = 1; off < 256; off <<= 1) {
        int t = (tid >= off) ? sm[tid - off] : 0;
        __syncthreads();
        sm[tid] += t;
        __syncthreads();
    }
    if (i < n) rowptr[i] = boffs[blockIdx.x] + sm[tid] - v;
}

// bucket entries: es2[pos] = (src, bitcast(dinv[src]))
__global__ void k_bucket(const int* __restrict__ src, const int* __restrict__ dst,
                         const float* __restrict__ dinv,
                         const int* __restrict__ rowptr, int* __restrict__ fill,
                         int2* __restrict__ es2, int E) {
    int e = blockIdx.x * 256 + threadIdx.x;
    if (e >= E) return;
    int d = dst[e], s = src[e];
    int pos = rowptr[d] + atomicAdd(&fill[d], 1);
    es2[pos] = make_int2(s, __float_as_int(dinv[s]));
}

// gather-aggregate: one wave per node; lane=(slot 0..7 edges, oct 0..7 bf16-octets)
__global__ __launch_bounds__(256) void k_agg(
    const ushort* __restrict__ xb, const float* __restrict__ dinv,
    const int2* __restrict__ es2, const int* __restrict__ rowptr,
    const int* __restrict__ deg, ushort* __restrict__ xaggb, int n) {
    int node = (blockIdx.x * 256 + threadIdx.x) >> 6;
    int lane = threadIdx.x & 63;
    if (node >= n) return;
    int slot = lane >> 3, oct = lane & 7;
    int start = rowptr[node], cnt = deg[node];
    float di = dinv[node];
    float a0 = 0.f, a1 = 0.f, a2 = 0.f, a3 = 0.f, a4 = 0.f, a5 = 0.f, a6 = 0.f, a7 = 0.f;
    for (int base = 0; base < cnt; base += 16) {
        int k0 = base + slot, k1 = base + slot + 8;
        bool v0 = k0 < cnt, v1 = k1 < cnt;
        int2 e0 = make_int2(0, 0), e1 = make_int2(0, 0);
        if (v0) e0 = es2[start + k0];
        if (v1) e1 = es2[start + k1];
        uint4 r0 = make_uint4(0u, 0u, 0u, 0u), r1 = make_uint4(0u, 0u, 0u, 0u);
        if (v0) r0 = *(const uint4*)(xb + (size_t)e0.x * F + oct * 8);
        if (v1) r1 = *(const uint4*)(xb + (size_t)e1.x * F + oct * 8);
        float w0 = v0 ? __int_as_float(e0.y) * di : 0.f;
        float w1 = v1 ? __int_as_float(e1.y) * di : 0.f;
        a0 += w0 * blo(r0.x) + w1 * blo(r1.x);
        a1 += w0 * bhi(r0.x) + w1 * bhi(r1.x);
        a2 += w0 * blo(r0.y) + w1 * blo(r1.y);
        a3 += w0 * bhi(r0.y) + w1 * bhi(r1.y);
        a4 += w0 * blo(r0.z) + w1 * blo(r1.z);
        a5 += w0 * bhi(r0.z) + w1 * bhi(r1.z);
        a6 += w0 * blo(r0.w) + w1 * blo(r1.w);
        a7 += w0 * bhi(r0.w) + w1 * bhi(r1.w);
    }
    a0 += __shfl_xor(a0, 8); a0 += __shfl_xor(a0, 16); a0 += __shfl_xor(a0, 32);
    a1 += __shfl_xor(a1, 8); a1 += __shfl_xor(a1, 16); a1 += __shfl_xor(a1, 32);
    a2 += __shfl_xor(a2, 8); a2 += __shfl_xor(a2, 16); a2 += __shfl_xor(a2, 32);
    a3 += __shfl_xor(a3, 8); a3 += __shfl_xor(a3, 16); a3 += __shfl_xor(a3, 32);
    a4 += __shfl_xor(a4, 8); a4 += __shfl_xor(a4, 16); a4 += __shfl_xor(a4, 32);
    a5 += __shfl_xor(a5, 8); a5 += __shfl_xor(a5, 16); a5 += __shfl_xor(a5, 32);
    a6 += __shfl_xor(a6, 8); a6 += __shfl_xor(a6, 16); a6 += __shfl_xor(a6, 32);
    a7 += __shfl_xor(a7, 8); a7 += __shfl_xor(a7, 16); a7 += __shfl_xor(a7, 32);
    if (slot == 0) {
        float dd = di * di;
        uint4 xv = *(const uint4*)(xb + (size_t)node * F + oct * 8);
        a0 += dd * blo(xv.x); a1 += dd * bhi(xv.x);
        a2 += dd * blo(xv.y); a3 += dd * bhi(xv.y);
        a4 += dd * blo(xv.z); a5 += dd * bhi(xv.z);
        a6 += dd * blo(xv.w); a7 += dd * bhi(xv.w);
        uint4 o;
        o.x = (uint)f2bf(a0) | ((uint)f2bf(a1) << 16);
        o.y = (uint)f2bf(a2) | ((uint)f2bf(a3) << 16);
        o.z = (uint)f2bf(a4) | ((uint)f2bf(a5) << 16);
        o.w = (uint)f2bf(a6) | ((uint)f2bf(a7) << 16);
        *(uint4*)(xaggb + (size_t)node * F + oct * 8) = o;
    }
}

// B1t[c][k] (bf16): c<64 -> Mz[k][c]; c>=64 -> Mh[k][c-64]. V = biases.
__global__ void k_weights(const float* __restrict__ Wz, const float* __restrict__ bz,
                          const float* __restrict__ Wh, const float* __restrict__ bh,
                          const float* __restrict__ Wlz, const float* __restrict__ blz,
                          const float* __restrict__ Wlh, const float* __restrict__ blh,
                          ushort* __restrict__ B1t, float* __restrict__ V) {
    int j = threadIdx.x;
    int k = blockIdx.x;
    if (k < 64) {
        float sz = 0.f, sh = 0.f;
        for (int i = 0; i < 64; ++i) {
            sz += Wz[k * 64 + i] * Wlz[i * 64 + j];
            sh += Wh[k * 64 + i] * Wlh[i * 64 + j];
        }
        B1t[j * 64 + k]        = f2bf(sz);
        B1t[(64 + j) * 64 + k] = f2bf(sh);
    } else {
        float sz = blz[j], sh = blh[j];
        for (int i = 0; i < 64; ++i) {
            sz += bz[i] * Wlz[i * 64 + j];
            sh += bh[i] * Wlh[i * 64 + j];
        }
        V[j]      = sz;
        V[64 + j] = sh;
    }
}

// B2t[c][k] (bf16): c<64 -> W1a[k][c]; c>=64 -> W1b[k][c-64]
// W1cTb[j][k] (bf16, [64][32]): = W1c[k][j] = W1[128+k][j]
__global__ void k_wcast(const float* __restrict__ W1, ushort* __restrict__ B2t,
                        ushort* __restrict__ W1cTb) {
    int i = blockIdx.x * 256 + threadIdx.x;
    if (i < 8192) {
        int c = i >> 6, k = i & 63;
        int row = (c < 64) ? k : (64 + k);
        B2t[i] = f2bf(W1[row * 64 + (c & 63)]);
    }
    int t = i - 8192;
    if (t >= 0 && t < 2048) {
        int j = t >> 5, k = t & 31;
        W1cTb[t] = f2bf(W1[(128 + k) * 64 + j]);
    }
}

// MFMA node kernel (unchanged from R5)
__global__ __launch_bounds__(256) void k_node(
    const ushort* __restrict__ xaggb, const ushort* __restrict__ B1t,
    const ushort* __restrict__ B2t, const float* __restrict__ V,
    const float* __restrict__ b1,
    ushort* __restrict__ Pb, ushort* __restrict__ Qb, int n) {
    __shared__ ushort hsm[64 * 64];
    int wid = threadIdx.x >> 6, lane = threadIdx.x & 63;
    int lg = lane >> 4, lc = lane & 15;
    int base = blockIdx.x * 64;

    bf16x8 b1f[2][2], b2f[2][2];
    #pragma unroll
    for (int t = 0; t < 2; ++t) {
        int c1 = ((t ? wid + 4 : wid) * 16 + lc) * 64;
        int c2 = ((wid * 2 + t) * 16 + lc) * 64;
        #pragma unroll
        for (int ks = 0; ks < 2; ++ks) {
            b1f[t][ks] = *(const bf16x8*)(B1t + c1 + ks * 32 + lg * 8);
            b2f[t][ks] = *(const bf16x8*)(B2t + c2 + ks * 32 + lg * 8);
        }
    }
    float vzc = V[wid * 16 + lc], vhc = V[64 + wid * 16 + lc];
    float bP[2];
    #pragma unroll
    for (int t = 0; t < 2; ++t) {
        int c2 = (wid * 2 + t) * 16 + lc;
        bP[t] = (c2 < 64) ? b1[c2] : 0.f;
    }

    const f32x4 fz = {0.f, 0.f, 0.f, 0.f};
    f32x4 accZ[4], accT[4];
    #pragma unroll
    for (int rt = 0; rt < 4; ++rt) { accZ[rt] = fz; accT[rt] = fz; }

    #pragma unroll
    for (int rt = 0; rt < 4; ++rt) {
        const ushort* ap = xaggb + (size_t)(base + rt * 16 + lc) * 64 + lg * 8;
        bf16x8 a0 = *(const bf16x8*)(ap);
        bf16x8 a1 = *(const bf16x8*)(ap + 32);
        accZ[rt] = __builtin_amdgcn_mfma_f32_16x16x32_bf16(a0, b1f[0][0], accZ[rt], 0, 0, 0);
        accZ[rt] = __builtin_amdgcn_mfma_f32_16x16x32_bf16(a1, b1f[0][1], accZ[rt], 0, 0, 0);
        accT[rt] = __builtin_amdgcn_mfma_f32_16x16x32_bf16(a0, b1f[1][0], accT[rt], 0, 0, 0);
        accT[rt] = __builtin_amdgcn_mfma_f32_16x16x32_bf16(a1, b1f[1][1], accT[rt], 0, 0, 0);
    }

    #pragma unroll
    for (int rt = 0; rt < 4; ++rt) {
        #pragma unroll
        for (int r = 0; r < 4; ++r) {
            float z = 1.f / (1.f + __expf(-(accZ[rt][r] + vzc)));
            float tt = tanhf(accT[rt][r] + vhc);
            float h = (1.f - z) * tt;
            int row = rt * 16 + lg * 4 + r;
            int byte = ((row * 64 + wid * 16 + lc) * 2) ^ ((row & 7) << 4);
            *(ushort*)((char*)hsm + byte) = f2bf(h);
        }
    }
    __syncthreads();

    f32x4 acc2[2][4];
    #pragma unroll
    for (int rt = 0; rt < 4; ++rt) { acc2[0][rt] = fz; acc2[1][rt] = fz; }
    #pragma unroll
    for (int rt = 0; rt < 4; ++rt) {
        #pragma unroll
        for (int ks = 0; ks < 2; ++ks) {
            int row = rt * 16 + lc;
            int byte = (row * 128 + ks * 64 + lg * 16) ^ ((row & 7) << 4);
            bf16x8 a2 = *(const bf16x8*)((char*)hsm + byte);
            acc2[0][rt] = __builtin_amdgcn_mfma_f32_16x16x32_bf16(a2, b2f[0][ks], acc2[0][rt], 0, 0, 0);
            acc2[1][rt] = __builtin_amdgcn_mfma_f32_16x16x32_bf16(a2, b2f[1][ks], acc2[1][rt], 0, 0, 0);
        }
    }

    ushort* dstb = (wid < 2) ? Pb : Qb;
    #pragma unroll
    for (int t = 0; t < 2; ++t) {
        int cl = ((wid * 2 + t) * 16 + lc) & 63;
        #pragma unroll
        for (int rt = 0; rt < 4; ++rt) {
            #pragma unroll
            for (int r = 0; r < 4; ++r) {
                int node = base + rt * 16 + lg * 4 + r;
                if (node < n) dstb[(size_t)node * 64 + cl] = f2bf(acc2[t][rt][r] + bP[t]);
            }
        }
    }
}

// Fused MFMA edge kernel, ORIGINAL order + NON-TEMPORAL streaming (R13 exact):
// attr/src/dst loads and out stores bypass cache retention -> P/Q stay L3-resident.
__global__ __launch_bounds__(256) void k_edge2(
    const int* __restrict__ src, const int* __restrict__ dst,
    const float* __restrict__ attr,
    const ushort* __restrict__ Pb, const ushort* __restrict__ Qb,
    const ushort* __restrict__ W1cTb,
    const float* __restrict__ W2, const float* __restrict__ b2,
    float* __restrict__ out, int E) {
    __shared__ float w2s[256];
    __shared__ float b2s[4];
    w2s[threadIdx.x] = W2[threadIdx.x];
    if (threadIdx.x < 4) b2s[threadIdx.x] = b2[threadIdx.x];
    __syncthreads();

    int wid = threadIdx.x >> 6, lane = threadIdx.x & 63;
    int lg = lane >> 4, lc = lane & 15;
    int we = (blockIdx.x * 4 + wid) * 64;
    if (we >= E) return;

    int idx = we + lane; if (idx >= E) idx = E - 1;
    int sR = __builtin_nontemporal_load(src + idx);
    int dR = __builtin_nontemporal_load(dst + idx);

    // A-frags: W1cT rows rt*16+lc, k = lg*8..+7
    bf16x8 aW[4];
    #pragma unroll
    for (int rt = 0; rt < 4; ++rt)
        aW[rt] = *(const bf16x8*)(W1cTb + (rt * 16 + lc) * 32 + lg * 8);

    const f32x4 fz = {0.f, 0.f, 0.f, 0.f};
    #pragma unroll
    for (int et = 0; et < 4; ++et) {
        int erow = et * 16 + lc;
        int eid_e = we + erow; if (eid_e >= E) eid_e = E - 1;
        int s_e = __shfl(sR, erow);
        int d_e = __shfl(dR, erow);

        // B-frag: attr[eid_e][lg*8 .. +7] -> bf16 (coalesced, non-temporal)
        const f32x4* ap = (const f32x4*)(attr + (size_t)eid_e * EF + lg * 8);
        f32x4 a0 = __builtin_nontemporal_load(ap);
        f32x4 a1 = __builtin_nontemporal_load(ap + 1);
        bf16x8 bfr;
        bfr[0] = (short)f2bf(a0.x); bfr[1] = (short)f2bf(a0.y);
        bfr[2] = (short)f2bf(a0.z); bfr[3] = (short)f2bf(a0.w);
        bfr[4] = (short)f2bf(a1.x); bfr[5] = (short)f2bf(a1.y);
        bfr[6] = (short)f2bf(a1.z); bfr[7] = (short)f2bf(a1.w);

        f32x4 acc[4];
        #pragma unroll
        for (int rt = 0; rt < 4; ++rt) acc[rt] = fz;
        #pragma unroll
        for (int rt = 0; rt < 4; ++rt)
            acc[rt] = __builtin_amdgcn_mfma_f32_16x16x32_bf16(aW[rt], bfr, acc[rt], 0, 0, 0);

        const ushort* Ps = Pb + (size_t)s_e * F;
        const ushort* Qd = Qb + (size_t)d_e * F;
        float o0 = 0.f, o1 = 0.f, o2 = 0.f, o3 = 0.f;
        #pragma unroll
        for (int rt = 0; rt < 4; ++rt) {
            int j0 = rt * 16 + lg * 4;
            uint2 pv = *(const uint2*)(Ps + j0);
            uint2 qv = *(const uint2*)(Qd + j0);
            float p0 = blo(pv.x), p1 = bhi(pv.x), p2 = blo(pv.y), p3 = bhi(pv.y);
            float q0 = blo(qv.x), q1 = bhi(qv.x), q2 = blo(qv.y), q3 = bhi(qv.y);
            float h0 = fmaxf(acc[rt][0] + p0 + q0, 0.f);
            float h1 = fmaxf(acc[rt][1] + p1 + q1, 0.f);
            float h2 = fmaxf(acc[rt][2] + p2 + q2, 0.f);
            float h3 = fmaxf(acc[rt][3] + p3 + q3, 0.f);
            float4 w0 = *(const float4*)(&w2s[(j0 + 0) * 4]);
            float4 w1 = *(const float4*)(&w2s[(j0 + 1) * 4]);
            float4 w2v = *(const float4*)(&w2s[(j0 + 2) * 4]);
            float4 w3 = *(const float4*)(&w2s[(j0 + 3) * 4]);
            o0 += h0 * w0.x + h1 * w1.x + h2 * w2v.x + h3 * w3.x;
            o1 += h0 * w0.y + h1 * w1.y + h2 * w2v.y + h3 * w3.y;
            o2 += h0 * w0.z + h1 * w1.z + h2 * w2v.z + h3 * w3.z;
            o3 += h0 * w0.w + h1 * w1.w + h2 * w2v.w + h3 * w3.w;
        }
        o0 += __shfl_xor(o0, 16); o0 += __shfl_xor(o0, 32);
        o1 += __shfl_xor(o1, 16); o1 += __shfl_xor(o1, 32);
        o2 += __shfl_xor(o2, 16); o2 += __shfl_xor(o2, 32);
        o3 += __shfl_xor(o3, 16); o3 += __shfl_xor(o3, 32);
        if (lg == 0 && (we + erow) < E) {
            f32x4 ov = {o0 + b2s[0], o1 + b2s[1], o2 + b2s[2], o3 + b2s[3]};
            __builtin_nontemporal_store(ov, (f32x4*)(out + (size_t)(we + erow) * 4));
        }
    }
}

// ---------------------------------------------------------------- launch

extern "C" void kernel_launch(void* const* d_in, const int* in_sizes, int n_in,
                              void* d_out, int out_size, void* d_ws, size_t ws_size,
                              hipStream_t stream) {
    const float* x    = (const float*)d_in[0];
    const int*   ei   = (const int*)d_in[1];
    const float* attr = (const float*)d_in[2];
    const float* Wz   = (const float*)d_in[3];
    const float* bz   = (const float*)d_in[4];
    const float* Wh   = (const float*)d_in[7];
    const float* bh   = (const float*)d_in[8];
    const float* Wlz  = (const float*)d_in[9];
    const float* blz  = (const float*)d_in[10];
    const float* Wlh  = (const float*)d_in[13];
    const float* blh  = (const float*)d_in[14];
    const float* W1   = (const float*)d_in[15];
    const float* b1   = (const float*)d_in[16];
    const float* W2   = (const float*)d_in[17];
    const float* b2   = (const float*)d_in[18];
    float* out = (float*)d_out;

    const int N = in_sizes[0] / F;
    const int E = in_sizes[1] / 2;
    const int* src = ei;
    const int* dst = ei + E;
    const int NB = (N + 255) / 256;
    const int NBT = (N + 63) / 64;

    // workspace layout; xb dead after k_agg -> Pb aliases it
    ushort* xaggb = (ushort*)d_ws;                      // N*F ushort
    ushort* regB  = xaggb + (size_t)N * F;              // N*F ushort: xb then Pb
    ushort* Qb    = regB + (size_t)N * F;               // N*F ushort
    ushort* B1t   = Qb + (size_t)N * F;                 // 8192
    ushort* B2t   = B1t + 8192;                         // 8192
    ushort* W1cTb = B2t + 8192;                         // 2048
    float*  V     = (float*)(W1cTb + 2048);             // 128
    int2*   es2   = (int2*)(V + 128);                   // E int2
    int*    deg   = (int*)(es2 + (size_t)E);            // N
    float*  dinv  = (float*)(deg + N);                  // N
    int*    rowptr= (int*)(dinv + N);                   // N
    int*    fill  = rowptr + N;                         // N
    int*    bsum  = fill + N;                           // <=512
    int*    boffs = bsum + 512;                         // <=512
    ushort* xb = regB;
    ushort* Pb = regB;

    hipMemsetAsync(deg, 0, (size_t)N * sizeof(int), stream);
    hipMemsetAsync(fill, 0, (size_t)N * sizeof(int), stream);

    k_deg<<<(E + 255) / 256, 256, 0, stream>>>(dst, deg, E);
    k_dinv<<<NB, 256, 0, stream>>>(deg, dinv, N);
    k_weights<<<65, 64, 0, stream>>>(Wz, bz, Wh, bh, Wlz, blz, Wlh, blh, B1t, V);
    k_wcast<<<40, 256, 0, stream>>>(W1, B2t, W1cTb);
    k_xcast<<<(N * F / 4 + 255) / 256, 256, 0, stream>>>(x, xb, N * F / 4);

    // CSR build
    k_blocksum<<<NB, 256, 0, stream>>>(deg, bsum, N);
    k_scanb<<<1, 64, 0, stream>>>(bsum, boffs, NB);
    k_rowptr<<<NB, 256, 0, stream>>>(deg, boffs, rowptr, N);
    k_bucket<<<(E + 255) / 256, 256, 0, stream>>>(src, dst, dinv, rowptr, fill, es2, E);

    k_agg<<<(N * 64 + 255) / 256, 256, 0, stream>>>(xb, dinv, es2, rowptr, deg, xaggb, N);

    k_node<<<NBT, 256, 0, stream>>>(xaggb, B1t, B2t, V, b1, Pb, Qb, N);

    k_edge2<<<(E + 255) / 256, 256, 0, stream>>>(src, dst, attr, Pb, Qb, W1cTb, W2, b2, out, E);
}

// Round 17
// 375.450 us; speedup vs baseline: 1.0764x; 1.0358x over previous
//
#include <hip/hip_runtime.h>

#define F 64      // F_IN == HID
#define EF 32
#define COUT 4
#define PQSC 32.0f        // fp8 encode scale for P/Q
#define PQISC 0.03125f    // 1/PQSC

typedef unsigned int uint;
typedef unsigned short ushort;
typedef unsigned char uchar;
typedef __attribute__((ext_vector_type(8))) short bf16x8;
typedef __attribute__((ext_vector_type(4))) float f32x4;

__device__ inline ushort f2bf(float f) {           // RNE float->bf16
    uint u = __float_as_uint(f);
    return (ushort)((u + 0x7fff + ((u >> 16) & 1)) >> 16);
}
__device__ inline float bf2f(ushort u) {
    return __uint_as_float(((uint)u) << 16);
}
__device__ inline float blo(uint u) { return __uint_as_float(u << 16); }
__device__ inline float bhi(uint u) { return __uint_as_float(u & 0xffff0000u); }
__device__ inline uchar f2fp8(float v) {           // HW cvt, saturating e4m3
    return (uchar)(__builtin_amdgcn_cvt_pk_fp8_f32(v, v, 0, false) & 0xff);
}

// ---------------------------------------------------------------- kernels

__global__ void k_deg(const int* __restrict__ dst, int* __restrict__ deg, int E) {
    int i = blockIdx.x * blockDim.x + threadIdx.x;
    if (i < E) atomicAdd(&deg[dst[i]], 1);
}

__global__ void k_dinv(const int* __restrict__ deg, float* __restrict__ dinv, int n) {
    int i = blockIdx.x * blockDim.x + threadIdx.x;
    if (i < n) dinv[i] = rsqrtf((float)(deg[i] + 1));
}

__global__ void k_xcast(const float* __restrict__ x, ushort* __restrict__ xb, int n4) {
    int i = blockIdx.x * 256 + threadIdx.x;
    if (i >= n4) return;
    f32x4 v = __builtin_nontemporal_load((const f32x4*)(x + (size_t)i * 4));
    ushort4 o;
    o.x = f2bf(v.x); o.y = f2bf(v.y); o.z = f2bf(v.z); o.w = f2bf(v.w);
    *(ushort4*)(xb + (size_t)i * 4) = o;
}

// ---- exclusive scan of deg -> rowptr ----

__global__ void k_blocksum(const int* __restrict__ deg, int* __restrict__ bsum, int n) {
    __shared__ int sm[256];
    int i = blockIdx.x * 256 + threadIdx.x;
    sm[threadIdx.x] = (i < n) ? deg[i] : 0;
    __syncthreads();
    for (int s = 128; s > 0; s >>= 1) {
        if (threadIdx.x < s) sm[threadIdx.x] += sm[threadIdx.x + s];
        __syncthreads();
    }
    if (threadIdx.x == 0) bsum[blockIdx.x] = sm[0];
}

__global__ void k_scanb(const int* __restrict__ bsum, int* __restrict__ boffs, int nb) {
    int lane = threadIdx.x;
    int carry = 0;
    for (int base = 0; base < nb; base += 64) {
        int v = (base + lane < nb) ? bsum[base + lane] : 0;
        int incl = v;
        #pragma unroll
        for (int off = 1; off < 64; off <<= 1) {
            int t = __shfl_up(incl, off);
            if (lane >= off) incl += t;
        }
        if (base + lane < nb) boffs[base + lane] = carry + incl - v;
        carry += __shfl(incl, 63);
    }
}

__global__ void k_rowptr(const int* __restrict__ deg, const int* __restrict__ boffs,
                         int* __restrict__ rowptr, int n) {
    __shared__ int sm[256];
    int tid = threadIdx.x;
    int i = blockIdx.x * 256 + tid;
    int v = (i < n) ? deg[i] : 0;
    sm[tid] = v;
    __syncthreads();
    for (int off = 1; off < 256; off <<= 1) {
        int t = (tid >= off) ? sm[tid - off] : 0;
        __syncthreads();
        sm[tid] += t;
        __syncthreads();
    }
    if (i < n) rowptr[i] = boffs[blockIdx.x] + sm[tid] - v;
}

// bucket entries: es2[pos] = (src, bitcast(dinv[src]))
__global__ void k_bucket(const int* __restrict__ src, const int* __restrict__ dst,
                         const float* __restrict__ dinv,
                         const int* __restrict__ rowptr, int* __restrict__ fill,
                         int2* __restrict__ es2, int E) {
    int e = blockIdx.x * 256 + threadIdx.x;
    if (e >= E) return;
    int d = dst[e], s = src[e];
    int pos = rowptr[d] + atomicAdd(&fill[d], 1);
    es2[pos] = make_int2(s, __float_as_int(dinv[s]));
}

// gather-aggregate: one wave per node; lane=(slot 0..7 edges, oct 0..7 bf16-octets)
__global__ __launch_bounds__(256) void k_agg(
    const ushort* __restrict__ xb, const float* __restrict__ dinv,
    const int2* __restrict__ es2, const int* __restrict__ rowptr,
    const int* __restrict__ deg, ushort* __restrict__ xaggb, int n) {
    int node = (blockIdx.x * 256 + threadIdx.x) >> 6;
    int lane = threadIdx.x & 63;
    if (node >= n) return;
    int slot = lane >> 3, oct = lane & 7;
    int start = rowptr[node], cnt = deg[node];
    float di = dinv[node];
    float a0 = 0.f, a1 = 0.f, a2 = 0.f, a3 = 0.f, a4 = 0.f, a5 = 0.f, a6 = 0.f, a7 = 0.f;
    for (int base = 0; base < cnt; base += 16) {
        int k0 = base + slot, k1 = base + slot + 8;
        bool v0 = k0 < cnt, v1 = k1 < cnt;
        int2 e0 = make_int2(0, 0), e1 = make_int2(0, 0);
        if (v0) e0 = es2[start + k0];
        if (v1) e1 = es2[start + k1];
        uint4 r0 = make_uint4(0u, 0u, 0u, 0u), r1 = make_uint4(0u, 0u, 0u, 0u);
        if (v0) r0 = *(const uint4*)(xb + (size_t)e0.x * F + oct * 8);
        if (v1) r1 = *(const uint4*)(xb + (size_t)e1.x * F + oct * 8);
        float w0 = v0 ? __int_as_float(e0.y) * di : 0.f;
        float w1 = v1 ? __int_as_float(e1.y) * di : 0.f;
        a0 += w0 * blo(r0.x) + w1 * blo(r1.x);
        a1 += w0 * bhi(r0.x) + w1 * bhi(r1.x);
        a2 += w0 * blo(r0.y) + w1 * blo(r1.y);
        a3 += w0 * bhi(r0.y) + w1 * bhi(r1.y);
        a4 += w0 * blo(r0.z) + w1 * blo(r1.z);
        a5 += w0 * bhi(r0.z) + w1 * bhi(r1.z);
        a6 += w0 * blo(r0.w) + w1 * blo(r1.w);
        a7 += w0 * bhi(r0.w) + w1 * bhi(r1.w);
    }
    a0 += __shfl_xor(a0, 8); a0 += __shfl_xor(a0, 16); a0 += __shfl_xor(a0, 32);
    a1 += __shfl_xor(a1, 8); a1 += __shfl_xor(a1, 16); a1 += __shfl_xor(a1, 32);
    a2 += __shfl_xor(a2, 8); a2 += __shfl_xor(a2, 16); a2 += __shfl_xor(a2, 32);
    a3 += __shfl_xor(a3, 8); a3 += __shfl_xor(a3, 16); a3 += __shfl_xor(a3, 32);
    a4 += __shfl_xor(a4, 8); a4 += __shfl_xor(a4, 16); a4 += __shfl_xor(a4, 32);
    a5 += __shfl_xor(a5, 8); a5 += __shfl_xor(a5, 16); a5 += __shfl_xor(a5, 32);
    a6 += __shfl_xor(a6, 8); a6 += __shfl_xor(a6, 16); a6 += __shfl_xor(a6, 32);
    a7 += __shfl_xor(a7, 8); a7 += __shfl_xor(a7, 16); a7 += __shfl_xor(a7, 32);
    if (slot == 0) {
        float dd = di * di;
        uint4 xv = *(const uint4*)(xb + (size_t)node * F + oct * 8);
        a0 += dd * blo(xv.x); a1 += dd * bhi(xv.x);
        a2 += dd * blo(xv.y); a3 += dd * bhi(xv.y);
        a4 += dd * blo(xv.z); a5 += dd * bhi(xv.z);
        a6 += dd * blo(xv.w); a7 += dd * bhi(xv.w);
        uint4 o;
        o.x = (uint)f2bf(a0) | ((uint)f2bf(a1) << 16);
        o.y = (uint)f2bf(a2) | ((uint)f2bf(a3) << 16);
        o.z = (uint)f2bf(a4) | ((uint)f2bf(a5) << 16);
        o.w = (uint)f2bf(a6) | ((uint)f2bf(a7) << 16);
        *(uint4*)(xaggb + (size_t)node * F + oct * 8) = o;
    }
}

// B1t[c][k] (bf16): c<64 -> Mz[k][c]; c>=64 -> Mh[k][c-64]. V = biases.
__global__ void k_weights(const float* __restrict__ Wz, const float* __restrict__ bz,
                          const float* __restrict__ Wh, const float* __restrict__ bh,
                          const float* __restrict__ Wlz, const float* __restrict__ blz,
                          const float* __restrict__ Wlh, const float* __restrict__ blh,
                          ushort* __restrict__ B1t, float* __restrict__ V) {
    int j = threadIdx.x;
    int k = blockIdx.x;
    if (k < 64) {
        float sz = 0.f, sh = 0.f;
        for (int i = 0; i < 64; ++i) {
            sz += Wz[k * 64 + i] * Wlz[i * 64 + j];
            sh += Wh[k * 64 + i] * Wlh[i * 64 + j];
        }
        B1t[j * 64 + k]        = f2bf(sz);
        B1t[(64 + j) * 64 + k] = f2bf(sh);
    } else {
        float sz = blz[j], sh = blh[j];
        for (int i = 0; i < 64; ++i) {
            sz += bz[i] * Wlz[i * 64 + j];
            sh += bh[i] * Wlh[i * 64 + j];
        }
        V[j]      = sz;
        V[64 + j] = sh;
    }
}

// B2t[c][k] (bf16): c<64 -> W1a[k][c]; c>=64 -> W1b[k][c-64]
// W1cTb[j][k] (bf16, [64][32]): = W1c[k][j] = W1[128+k][j]
__global__ void k_wcast(const float* __restrict__ W1, ushort* __restrict__ B2t,
                        ushort* __restrict__ W1cTb) {
    int i = blockIdx.x * 256 + threadIdx.x;
    if (i < 8192) {
        int c = i >> 6, k = i & 63;
        int row = (c < 64) ? k : (64 + k);
        B2t[i] = f2bf(W1[row * 64 + (c & 63)]);
    }
    int t = i - 8192;
    if (t >= 0 && t < 2048) {
        int j = t >> 5, k = t & 31;
        W1cTb[t] = f2bf(W1[(128 + k) * 64 + j]);
    }
}

// MFMA node kernel; P/Q stored as fp8 e4m3 scaled by PQSC.
__global__ __launch_bounds__(256) void k_node(
    const ushort* __restrict__ xaggb, const ushort* __restrict__ B1t,
    const ushort* __restrict__ B2t, const float* __restrict__ V,
    const float* __restrict__ b1,
    uchar* __restrict__ Pb, uchar* __restrict__ Qb, int n) {
    __shared__ ushort hsm[64 * 64];
    int wid = threadIdx.x >> 6, lane = threadIdx.x & 63;
    int lg = lane >> 4, lc = lane & 15;
    int base = blockIdx.x * 64;

    bf16x8 b1f[2][2], b2f[2][2];
    #pragma unroll
    for (int t = 0; t < 2; ++t) {
        int c1 = ((t ? wid + 4 : wid) * 16 + lc) * 64;
        int c2 = ((wid * 2 + t) * 16 + lc) * 64;
        #pragma unroll
        for (int ks = 0; ks < 2; ++ks) {
            b1f[t][ks] = *(const bf16x8*)(B1t + c1 + ks * 32 + lg * 8);
            b2f[t][ks] = *(const bf16x8*)(B2t + c2 + ks * 32 + lg * 8);
        }
    }
    float vzc = V[wid * 16 + lc], vhc = V[64 + wid * 16 + lc];
    float bP[2];
    #pragma unroll
    for (int t = 0; t < 2; ++t) {
        int c2 = (wid * 2 + t) * 16 + lc;
        bP[t] = (c2 < 64) ? b1[c2] : 0.f;
    }

    const f32x4 fz = {0.f, 0.f, 0.f, 0.f};
    f32x4 accZ[4], accT[4];
    #pragma unroll
    for (int rt = 0; rt < 4; ++rt) { accZ[rt] = fz; accT[rt] = fz; }

    #pragma unroll
    for (int rt = 0; rt < 4; ++rt) {
        const ushort* ap = xaggb + (size_t)(base + rt * 16 + lc) * 64 + lg * 8;
        bf16x8 a0 = *(const bf16x8*)(ap);
        bf16x8 a1 = *(const bf16x8*)(ap + 32);
        accZ[rt] = __builtin_amdgcn_mfma_f32_16x16x32_bf16(a0, b1f[0][0], accZ[rt], 0, 0, 0);
        accZ[rt] = __builtin_amdgcn_mfma_f32_16x16x32_bf16(a1, b1f[0][1], accZ[rt], 0, 0, 0);
        accT[rt] = __builtin_amdgcn_mfma_f32_16x16x32_bf16(a0, b1f[1][0], accT[rt], 0, 0, 0);
        accT[rt] = __builtin_amdgcn_mfma_f32_16x16x32_bf16(a1, b1f[1][1], accT[rt], 0, 0, 0);
    }

    #pragma unroll
    for (int rt = 0; rt < 4; ++rt) {
        #pragma unroll
        for (int r = 0; r < 4; ++r) {
            float z = 1.f / (1.f + __expf(-(accZ[rt][r] + vzc)));
            float tt = tanhf(accT[rt][r] + vhc);
            float h = (1.f - z) * tt;
            int row = rt * 16 + lg * 4 + r;
            int byte = ((row * 64 + wid * 16 + lc) * 2) ^ ((row & 7) << 4);
            *(ushort*)((char*)hsm + byte) = f2bf(h);
        }
    }
    __syncthreads();

    f32x4 acc2[2][4];
    #pragma unroll
    for (int rt = 0; rt < 4; ++rt) { acc2[0][rt] = fz; acc2[1][rt] = fz; }
    #pragma unroll
    for (int rt = 0; rt < 4; ++rt) {
        #pragma unroll
        for (int ks = 0; ks < 2; ++ks) {
            int row = rt * 16 + lc;
            int byte = (row * 128 + ks * 64 + lg * 16) ^ ((row & 7) << 4);
            bf16x8 a2 = *(const bf16x8*)((char*)hsm + byte);
            acc2[0][rt] = __builtin_amdgcn_mfma_f32_16x16x32_bf16(a2, b2f[0][ks], acc2[0][rt], 0, 0, 0);
            acc2[1][rt] = __builtin_amdgcn_mfma_f32_16x16x32_bf16(a2, b2f[1][ks], acc2[1][rt], 0, 0, 0);
        }
    }

    uchar* dstb = (wid < 2) ? Pb : Qb;
    #pragma unroll
    for (int t = 0; t < 2; ++t) {
        int cl = ((wid * 2 + t) * 16 + lc) & 63;
        #pragma unroll
        for (int rt = 0; rt < 4; ++rt) {
            #pragma unroll
            for (int r = 0; r < 4; ++r) {
                int node = base + rt * 16 + lg * 4 + r;
                if (node < n)
                    dstb[(size_t)node * 64 + cl] = f2fp8((acc2[t][rt][r] + bP[t]) * PQSC);
            }
        }
    }
}

// Fused MFMA edge kernel: original order + nt streaming; P/Q gathered as fp8
// (64 B row = ONE cache line; per-edge line count 6 -> 4).
__global__ __launch_bounds__(256) void k_edge2(
    const int* __restrict__ src, const int* __restrict__ dst,
    const float* __restrict__ attr,
    const uchar* __restrict__ Pb, const uchar* __restrict__ Qb,
    const ushort* __restrict__ W1cTb,
    const float* __restrict__ W2, const float* __restrict__ b2,
    float* __restrict__ out, int E) {
    __shared__ float w2s[256];
    __shared__ float b2s[4];
    w2s[threadIdx.x] = W2[threadIdx.x];
    if (threadIdx.x < 4) b2s[threadIdx.x] = b2[threadIdx.x];
    __syncthreads();

    int wid = threadIdx.x >> 6, lane = threadIdx.x & 63;
    int lg = lane >> 4, lc = lane & 15;
    int we = (blockIdx.x * 4 + wid) * 64;
    if (we >= E) return;

    int idx = we + lane; if (idx >= E) idx = E - 1;
    int sR = __builtin_nontemporal_load(src + idx);
    int dR = __builtin_nontemporal_load(dst + idx);

    // A-frags: W1cT rows rt*16+lc, k = lg*8..+7
    bf16x8 aW[4];
    #pragma unroll
    for (int rt = 0; rt < 4; ++rt)
        aW[rt] = *(const bf16x8*)(W1cTb + (rt * 16 + lc) * 32 + lg * 8);

    const f32x4 fz = {0.f, 0.f, 0.f, 0.f};
    #pragma unroll
    for (int et = 0; et < 4; ++et) {
        int erow = et * 16 + lc;
        int eid_e = we + erow; if (eid_e >= E) eid_e = E - 1;
        int s_e = __shfl(sR, erow);
        int d_e = __shfl(dR, erow);

        // B-frag: attr[eid_e][lg*8 .. +7] -> bf16 (coalesced, non-temporal)
        const f32x4* ap = (const f32x4*)(attr + (size_t)eid_e * EF + lg * 8);
        f32x4 a0 = __builtin_nontemporal_load(ap);
        f32x4 a1 = __builtin_nontemporal_load(ap + 1);
        bf16x8 bfr;
        bfr[0] = (short)f2bf(a0.x); bfr[1] = (short)f2bf(a0.y);
        bfr[2] = (short)f2bf(a0.z); bfr[3] = (short)f2bf(a0.w);
        bfr[4] = (short)f2bf(a1.x); bfr[5] = (short)f2bf(a1.y);
        bfr[6] = (short)f2bf(a1.z); bfr[7] = (short)f2bf(a1.w);

        f32x4 acc[4];
        #pragma unroll
        for (int rt = 0; rt < 4; ++rt) acc[rt] = fz;
        #pragma unroll
        for (int rt = 0; rt < 4; ++rt)
            acc[rt] = __builtin_amdgcn_mfma_f32_16x16x32_bf16(aW[rt], bfr, acc[rt], 0, 0, 0);

        const uchar* Ps = Pb + (size_t)s_e * F;
        const uchar* Qd = Qb + (size_t)d_e * F;
        float o0 = 0.f, o1 = 0.f, o2 = 0.f, o3 = 0.f;
        #pragma unroll
        for (int rt = 0; rt < 4; ++rt) {
            int j0 = rt * 16 + lg * 4;
            uint pv = *(const uint*)(Ps + j0);
            uint qv = *(const uint*)(Qd + j0);
            float p0 = __builtin_amdgcn_cvt_f32_fp8(pv, 0);
            float p1 = __builtin_amdgcn_cvt_f32_fp8(pv, 1);
            float p2 = __builtin_amdgcn_cvt_f32_fp8(pv, 2);
            float p3 = __builtin_amdgcn_cvt_f32_fp8(pv, 3);
            float q0 = __builtin_amdgcn_cvt_f32_fp8(qv, 0);
            float q1 = __builtin_amdgcn_cvt_f32_fp8(qv, 1);
            float q2 = __builtin_amdgcn_cvt_f32_fp8(qv, 2);
            float q3 = __builtin_amdgcn_cvt_f32_fp8(qv, 3);
            float h0 = fmaxf(acc[rt][0] + (p0 + q0) * PQISC, 0.f);
            float h1 = fmaxf(acc[rt][1] + (p1 + q1) * PQISC, 0.f);
            float h2 = fmaxf(acc[rt][2] + (p2 + q2) * PQISC, 0.f);
            float h3 = fmaxf(acc[rt][3] + (p3 + q3) * PQISC, 0.f);
            float4 w0 = *(const float4*)(&w2s[(j0 + 0) * 4]);
            float4 w1 = *(const float4*)(&w2s[(j0 + 1) * 4]);
            float4 w2v = *(const float4*)(&w2s[(j0 + 2) * 4]);
            float4 w3 = *(const float4*)(&w2s[(j0 + 3) * 4]);
            o0 += h0 * w0.x + h1 * w1.x + h2 * w2v.x + h3 * w3.x;
            o1 += h0 * w0.y + h1 * w1.y + h2 * w2v.y + h3 * w3.y;
            o2 += h0 * w0.z + h1 * w1.z + h2 * w2v.z + h3 * w3.z;
            o3 += h0 * w0.w + h1 * w1.w + h2 * w2v.w + h3 * w3.w;
        }
        o0 += __shfl_xor(o0, 16); o0 += __shfl_xor(o0, 32);
        o1 += __shfl_xor(o1, 16); o1 += __shfl_xor(o1, 32);
        o2 += __shfl_xor(o2, 16); o2 += __shfl_xor(o2, 32);
        o3 += __shfl_xor(o3, 16); o3 += __shfl_xor(o3, 32);
        if (lg == 0 && (we + erow) < E) {
            f32x4 ov = {o0 + b2s[0], o1 + b2s[1], o2 + b2s[2], o3 + b2s[3]};
            __builtin_nontemporal_store(ov, (f32x4*)(out + (size_t)(we + erow) * 4));
        }
    }
}

// ---------------------------------------------------------------- launch

extern "C" void kernel_launch(void* const* d_in, const int* in_sizes, int n_in,
                              void* d_out, int out_size, void* d_ws, size_t ws_size,
                              hipStream_t stream) {
    const float* x    = (const float*)d_in[0];
    const int*   ei   = (const int*)d_in[1];
    const float* attr = (const float*)d_in[2];
    const float* Wz   = (const float*)d_in[3];
    const float* bz   = (const float*)d_in[4];
    const float* Wh   = (const float*)d_in[7];
    const float* bh   = (const float*)d_in[8];
    const float* Wlz  = (const float*)d_in[9];
    const float* blz  = (const float*)d_in[10];
    const float* Wlh  = (const float*)d_in[13];
    const float* blh  = (const float*)d_in[14];
    const float* W1   = (const float*)d_in[15];
    const float* b1   = (const float*)d_in[16];
    const float* W2   = (const float*)d_in[17];
    const float* b2   = (const float*)d_in[18];
    float* out = (float*)d_out;

    const int N = in_sizes[0] / F;
    const int E = in_sizes[1] / 2;
    const int* src = ei;
    const int* dst = ei + E;
    const int NB = (N + 255) / 256;
    const int NBT = (N + 63) / 64;

    // workspace layout; xb dead after k_agg -> Pb8 aliases it
    ushort* xaggb = (ushort*)d_ws;                      // N*F ushort
    ushort* regB  = xaggb + (size_t)N * F;              // N*F ushort: xb then Pb8
    ushort* QbR   = regB + (size_t)N * F;               // N*F ushort region: Qb8
    ushort* B1t   = QbR + (size_t)N * F;                // 8192
    ushort* B2t   = B1t + 8192;                         // 8192
    ushort* W1cTb = B2t + 8192;                         // 2048
    float*  V     = (float*)(W1cTb + 2048);             // 128
    int2*   es2   = (int2*)(V + 128);                   // E int2
    int*    deg   = (int*)(es2 + (size_t)E);            // N
    float*  dinv  = (float*)(deg + N);                  // N
    int*    rowptr= (int*)(dinv + N);                   // N
    int*    fill  = rowptr + N;                         // N
    int*    bsum  = fill + N;                           // <=512
    int*    boffs = bsum + 512;                         // <=512
    ushort* xb  = regB;
    uchar*  Pb8 = (uchar*)regB;
    uchar*  Qb8 = (uchar*)QbR;

    hipMemsetAsync(deg, 0, (size_t)N * sizeof(int), stream);
    hipMemsetAsync(fill, 0, (size_t)N * sizeof(int), stream);

    k_deg<<<(E + 255) / 256, 256, 0, stream>>>(dst, deg, E);
    k_dinv<<<NB, 256, 0, stream>>>(deg, dinv, N);
    k_weights<<<65, 64, 0, stream>>>(Wz, bz, Wh, bh, Wlz, blz, Wlh, blh, B1t, V);
    k_wcast<<<40, 256, 0, stream>>>(W1, B2t, W1cTb);
    k_xcast<<<(N * F / 4 + 255) / 256, 256, 0, stream>>>(x, xb, N * F / 4);

    // CSR build
    k_blocksum<<<NB, 256, 0, stream>>>(deg, bsum, N);
    k_scanb<<<1, 64, 0, stream>>>(bsum, boffs, NB);
    k_rowptr<<<NB, 256, 0, stream>>>(deg, boffs, rowptr, N);
    k_bucket<<<(E + 255) / 256, 256, 0, stream>>>(src, dst, dinv, rowptr, fill, es2, E);

    k_agg<<<(N * 64 + 255) / 256, 256, 0, stream>>>(xb, dinv, es2, rowptr, deg, xaggb, N);

    k_node<<<NBT, 256, 0, stream>>>(xaggb, B1t, B2t, V, b1, Pb8, Qb8, N);

    k_edge2<<<(E + 255) / 256, 256, 0, stream>>>(src, dst, attr, Pb8, Qb8, W1cTb, W2, b2, out, E);
}

// Round 18
// 371.873 us; speedup vs baseline: 1.0868x; 1.0096x over previous
//
#include <hip/hip_runtime.h>

#define F 64      // F_IN == HID
#define EF 32
#define COUT 4
#define PQSC 32.0f        // fp8 encode scale for P/Q
#define PQISC 0.03125f    // 1/PQSC
#define XSC 16.0f         // fp8 encode scale for x
#define XISC 0.0625f      // 1/XSC

typedef unsigned int uint;
typedef unsigned short ushort;
typedef unsigned char uchar;
typedef __attribute__((ext_vector_type(8))) short bf16x8;
typedef __attribute__((ext_vector_type(4))) float f32x4;

__device__ inline ushort f2bf(float f) {           // RNE float->bf16
    uint u = __float_as_uint(f);
    return (ushort)((u + 0x7fff + ((u >> 16) & 1)) >> 16);
}
__device__ inline float bf2f(ushort u) {
    return __uint_as_float(((uint)u) << 16);
}
__device__ inline float blo(uint u) { return __uint_as_float(u << 16); }
__device__ inline float bhi(uint u) { return __uint_as_float(u & 0xffff0000u); }
__device__ inline uchar f2fp8(float v) {           // HW cvt, saturating e4m3
    return (uchar)(__builtin_amdgcn_cvt_pk_fp8_f32(v, v, 0, false) & 0xff);
}

// ---------------------------------------------------------------- kernels

__global__ void k_deg(const int* __restrict__ dst, int* __restrict__ deg, int E) {
    int i = blockIdx.x * blockDim.x + threadIdx.x;
    if (i < E) atomicAdd(&deg[dst[i]], 1);
}

__global__ void k_dinv(const int* __restrict__ deg, float* __restrict__ dinv, int n) {
    int i = blockIdx.x * blockDim.x + threadIdx.x;
    if (i < n) dinv[i] = rsqrtf((float)(deg[i] + 1));
}

// x -> fp8 e4m3 (scaled by XSC); 8 elems/thread
__global__ void k_xcast(const float* __restrict__ x, uchar* __restrict__ xb8, int n8) {
    int i = blockIdx.x * 256 + threadIdx.x;
    if (i >= n8) return;
    f32x4 a = __builtin_nontemporal_load((const f32x4*)(x + (size_t)i * 8));
    f32x4 b = __builtin_nontemporal_load((const f32x4*)(x + (size_t)i * 8 + 4));
    uint lo = 0, hi = 0;
    lo = __builtin_amdgcn_cvt_pk_fp8_f32(a.x * XSC, a.y * XSC, lo, false);
    lo = __builtin_amdgcn_cvt_pk_fp8_f32(a.z * XSC, a.w * XSC, lo, true);
    hi = __builtin_amdgcn_cvt_pk_fp8_f32(b.x * XSC, b.y * XSC, hi, false);
    hi = __builtin_amdgcn_cvt_pk_fp8_f32(b.z * XSC, b.w * XSC, hi, true);
    *(uint2*)(xb8 + (size_t)i * 8) = make_uint2(lo, hi);
}

// ---- exclusive scan of deg -> rowptr ----

__global__ void k_blocksum(const int* __restrict__ deg, int* __restrict__ bsum, int n) {
    __shared__ int sm[256];
    int i = blockIdx.x * 256 + threadIdx.x;
    sm[threadIdx.x] = (i < n) ? deg[i] : 0;
    __syncthreads();
    for (int s = 128; s > 0; s >>= 1) {
        if (threadIdx.x < s) sm[threadIdx.x] += sm[threadIdx.x + s];
        __syncthreads();
    }
    if (threadIdx.x == 0) bsum[blockIdx.x] = sm[0];
}

__global__ void k_scanb(const int* __restrict__ bsum, int* __restrict__ boffs, int nb) {
    int lane = threadIdx.x;
    int carry = 0;
    for (int base = 0; base < nb; base += 64) {
        int v = (base + lane < nb) ? bsum[base + lane] : 0;
        int incl = v;
        #pragma unroll
        for (int off = 1; off < 64; off <<= 1) {
            int t = __shfl_up(incl, off);
            if (lane >= off) incl += t;
        }
        if (base + lane < nb) boffs[base + lane] = carry + incl - v;
        carry += __shfl(incl, 63);
    }
}

__global__ void k_rowptr(const int* __restrict__ deg, const int* __restrict__ boffs,
                         int* __restrict__ rowptr, int n) {
    __shared__ int sm[256];
    int tid = threadIdx.x;
    int i = blockIdx.x * 256 + tid;
    int v = (i < n) ? deg[i] : 0;
    sm[tid] = v;
    __syncthreads();
    for (int off = 1; off < 256; off <<= 1) {
        int t = (tid >= off) ? sm[tid - off] : 0;
        __syncthreads();
        sm[tid] += t;
        __syncthreads();
    }
    if (i < n) rowptr[i] = boffs[blockIdx.x] + sm[tid] - v;
}

// bucket entries: es2[pos] = (src, bitcast(dinv[src]))
__global__ void k_bucket(const int* __restrict__ src, const int* __restrict__ dst,
                         const float* __restrict__ dinv,
                         const int* __restrict__ rowptr, int* __restrict__ fill,
                         int2* __restrict__ es2, int E) {
    int e = blockIdx.x * 256 + threadIdx.x;
    if (e >= E) return;
    int d = dst[e], s = src[e];
    int pos = rowptr[d] + atomicAdd(&fill[d], 1);
    es2[pos] = make_int2(s, __float_as_int(dinv[s]));
}

// gather-aggregate: one wave per node; lane=(slot 0..7 edges, oct 0..7 octets)
// x rows gathered as fp8 (64 B = ONE cache line per row).
__global__ __launch_bounds__(256) void k_agg(
    const uchar* __restrict__ xb8, const float* __restrict__ dinv,
    const int2* __restrict__ es2, const int* __restrict__ rowptr,
    const int* __restrict__ deg, ushort* __restrict__ xaggb, int n) {
    int node = (blockIdx.x * 256 + threadIdx.x) >> 6;
    int lane = threadIdx.x & 63;
    if (node >= n) return;
    int slot = lane >> 3, oct = lane & 7;
    int start = rowptr[node], cnt = deg[node];
    float di = dinv[node];
    float a0 = 0.f, a1 = 0.f, a2 = 0.f, a3 = 0.f, a4 = 0.f, a5 = 0.f, a6 = 0.f, a7 = 0.f;
    for (int base = 0; base < cnt; base += 16) {
        int k0 = base + slot, k1 = base + slot + 8;
        bool v0 = k0 < cnt, v1 = k1 < cnt;
        int2 e0 = make_int2(0, 0), e1 = make_int2(0, 0);
        if (v0) e0 = es2[start + k0];
        if (v1) e1 = es2[start + k1];
        uint2 r0 = make_uint2(0u, 0u), r1 = make_uint2(0u, 0u);
        if (v0) r0 = *(const uint2*)(xb8 + (size_t)e0.x * F + oct * 8);
        if (v1) r1 = *(const uint2*)(xb8 + (size_t)e1.x * F + oct * 8);
        float w0 = v0 ? __int_as_float(e0.y) * di * XISC : 0.f;
        float w1 = v1 ? __int_as_float(e1.y) * di * XISC : 0.f;
        a0 += w0 * __builtin_amdgcn_cvt_f32_fp8(r0.x, 0) + w1 * __builtin_amdgcn_cvt_f32_fp8(r1.x, 0);
        a1 += w0 * __builtin_amdgcn_cvt_f32_fp8(r0.x, 1) + w1 * __builtin_amdgcn_cvt_f32_fp8(r1.x, 1);
        a2 += w0 * __builtin_amdgcn_cvt_f32_fp8(r0.x, 2) + w1 * __builtin_amdgcn_cvt_f32_fp8(r1.x, 2);
        a3 += w0 * __builtin_amdgcn_cvt_f32_fp8(r0.x, 3) + w1 * __builtin_amdgcn_cvt_f32_fp8(r1.x, 3);
        a4 += w0 * __builtin_amdgcn_cvt_f32_fp8(r0.y, 0) + w1 * __builtin_amdgcn_cvt_f32_fp8(r1.y, 0);
        a5 += w0 * __builtin_amdgcn_cvt_f32_fp8(r0.y, 1) + w1 * __builtin_amdgcn_cvt_f32_fp8(r1.y, 1);
        a6 += w0 * __builtin_amdgcn_cvt_f32_fp8(r0.y, 2) + w1 * __builtin_amdgcn_cvt_f32_fp8(r1.y, 2);
        a7 += w0 * __builtin_amdgcn_cvt_f32_fp8(r0.y, 3) + w1 * __builtin_amdgcn_cvt_f32_fp8(r1.y, 3);
    }
    a0 += __shfl_xor(a0, 8); a0 += __shfl_xor(a0, 16); a0 += __shfl_xor(a0, 32);
    a1 += __shfl_xor(a1, 8); a1 += __shfl_xor(a1, 16); a1 += __shfl_xor(a1, 32);
    a2 += __shfl_xor(a2, 8); a2 += __shfl_xor(a2, 16); a2 += __shfl_xor(a2, 32);
    a3 += __shfl_xor(a3, 8); a3 += __shfl_xor(a3, 16); a3 += __shfl_xor(a3, 32);
    a4 += __shfl_xor(a4, 8); a4 += __shfl_xor(a4, 16); a4 += __shfl_xor(a4, 32);
    a5 += __shfl_xor(a5, 8); a5 += __shfl_xor(a5, 16); a5 += __shfl_xor(a5, 32);
    a6 += __shfl_xor(a6, 8); a6 += __shfl_xor(a6, 16); a6 += __shfl_xor(a6, 32);
    a7 += __shfl_xor(a7, 8); a7 += __shfl_xor(a7, 16); a7 += __shfl_xor(a7, 32);
    if (slot == 0) {
        float dd = di * di * XISC;
        uint2 xv = *(const uint2*)(xb8 + (size_t)node * F + oct * 8);
        a0 += dd * __builtin_amdgcn_cvt_f32_fp8(xv.x, 0);
        a1 += dd * __builtin_amdgcn_cvt_f32_fp8(xv.x, 1);
        a2 += dd * __builtin_amdgcn_cvt_f32_fp8(xv.x, 2);
        a3 += dd * __builtin_amdgcn_cvt_f32_fp8(xv.x, 3);
        a4 += dd * __builtin_amdgcn_cvt_f32_fp8(xv.y, 0);
        a5 += dd * __builtin_amdgcn_cvt_f32_fp8(xv.y, 1);
        a6 += dd * __builtin_amdgcn_cvt_f32_fp8(xv.y, 2);
        a7 += dd * __builtin_amdgcn_cvt_f32_fp8(xv.y, 3);
        uint4 o;
        o.x = (uint)f2bf(a0) | ((uint)f2bf(a1) << 16);
        o.y = (uint)f2bf(a2) | ((uint)f2bf(a3) << 16);
        o.z = (uint)f2bf(a4) | ((uint)f2bf(a5) << 16);
        o.w = (uint)f2bf(a6) | ((uint)f2bf(a7) << 16);
        *(uint4*)(xaggb + (size_t)node * F + oct * 8) = o;
    }
}

// B1t[c][k] (bf16): c<64 -> Mz[k][c]; c>=64 -> Mh[k][c-64]. V = biases.
__global__ void k_weights(const float* __restrict__ Wz, const float* __restrict__ bz,
                          const float* __restrict__ Wh, const float* __restrict__ bh,
                          const float* __restrict__ Wlz, const float* __restrict__ blz,
                          const float* __restrict__ Wlh, const float* __restrict__ blh,
                          ushort* __restrict__ B1t, float* __restrict__ V) {
    int j = threadIdx.x;
    int k = blockIdx.x;
    if (k < 64) {
        float sz = 0.f, sh = 0.f;
        for (int i = 0; i < 64; ++i) {
            sz += Wz[k * 64 + i] * Wlz[i * 64 + j];
            sh += Wh[k * 64 + i] * Wlh[i * 64 + j];
        }
        B1t[j * 64 + k]        = f2bf(sz);
        B1t[(64 + j) * 64 + k] = f2bf(sh);
    } else {
        float sz = blz[j], sh = blh[j];
        for (int i = 0; i < 64; ++i) {
            sz += bz[i] * Wlz[i * 64 + j];
            sh += bh[i] * Wlh[i * 64 + j];
        }
        V[j]      = sz;
        V[64 + j] = sh;
    }
}

// B2t[c][k] (bf16): c<64 -> W1a[k][c]; c>=64 -> W1b[k][c-64]
// W1cTb[j][k] (bf16, [64][32]): = W1c[k][j] = W1[128+k][j]
__global__ void k_wcast(const float* __restrict__ W1, ushort* __restrict__ B2t,
                        ushort* __restrict__ W1cTb) {
    int i = blockIdx.x * 256 + threadIdx.x;
    if (i < 8192) {
        int c = i >> 6, k = i & 63;
        int row = (c < 64) ? k : (64 + k);
        B2t[i] = f2bf(W1[row * 64 + (c & 63)]);
    }
    int t = i - 8192;
    if (t >= 0 && t < 2048) {
        int j = t >> 5, k = t & 31;
        W1cTb[t] = f2bf(W1[(128 + k) * 64 + j]);
    }
}

// MFMA node kernel; P/Q stored as fp8 e4m3 scaled by PQSC.
__global__ __launch_bounds__(256) void k_node(
    const ushort* __restrict__ xaggb, const ushort* __restrict__ B1t,
    const ushort* __restrict__ B2t, const float* __restrict__ V,
    const float* __restrict__ b1,
    uchar* __restrict__ Pb, uchar* __restrict__ Qb, int n) {
    __shared__ ushort hsm[64 * 64];
    int wid = threadIdx.x >> 6, lane = threadIdx.x & 63;
    int lg = lane >> 4, lc = lane & 15;
    int base = blockIdx.x * 64;

    bf16x8 b1f[2][2], b2f[2][2];
    #pragma unroll
    for (int t = 0; t < 2; ++t) {
        int c1 = ((t ? wid + 4 : wid) * 16 + lc) * 64;
        int c2 = ((wid * 2 + t) * 16 + lc) * 64;
        #pragma unroll
        for (int ks = 0; ks < 2; ++ks) {
            b1f[t][ks] = *(const bf16x8*)(B1t + c1 + ks * 32 + lg * 8);
            b2f[t][ks] = *(const bf16x8*)(B2t + c2 + ks * 32 + lg * 8);
        }
    }
    float vzc = V[wid * 16 + lc], vhc = V[64 + wid * 16 + lc];
    float bP[2];
    #pragma unroll
    for (int t = 0; t < 2; ++t) {
        int c2 = (wid * 2 + t) * 16 + lc;
        bP[t] = (c2 < 64) ? b1[c2] : 0.f;
    }

    const f32x4 fz = {0.f, 0.f, 0.f, 0.f};
    f32x4 accZ[4], accT[4];
    #pragma unroll
    for (int rt = 0; rt < 4; ++rt) { accZ[rt] = fz; accT[rt] = fz; }

    #pragma unroll
    for (int rt = 0; rt < 4; ++rt) {
        const ushort* ap = xaggb + (size_t)(base + rt * 16 + lc) * 64 + lg * 8;
        bf16x8 a0 = *(const bf16x8*)(ap);
        bf16x8 a1 = *(const bf16x8*)(ap + 32);
        accZ[rt] = __builtin_amdgcn_mfma_f32_16x16x32_bf16(a0, b1f[0][0], accZ[rt], 0, 0, 0);
        accZ[rt] = __builtin_amdgcn_mfma_f32_16x16x32_bf16(a1, b1f[0][1], accZ[rt], 0, 0, 0);
        accT[rt] = __builtin_amdgcn_mfma_f32_16x16x32_bf16(a0, b1f[1][0], accT[rt], 0, 0, 0);
        accT[rt] = __builtin_amdgcn_mfma_f32_16x16x32_bf16(a1, b1f[1][1], accT[rt], 0, 0, 0);
    }

    #pragma unroll
    for (int rt = 0; rt < 4; ++rt) {
        #pragma unroll
        for (int r = 0; r < 4; ++r) {
            float z = 1.f / (1.f + __expf(-(accZ[rt][r] + vzc)));
            float tt = tanhf(accT[rt][r] + vhc);
            float h = (1.f - z) * tt;
            int row = rt * 16 + lg * 4 + r;
            int byte = ((row * 64 + wid * 16 + lc) * 2) ^ ((row & 7) << 4);
            *(ushort*)((char*)hsm + byte) = f2bf(h);
        }
    }
    __syncthreads();

    f32x4 acc2[2][4];
    #pragma unroll
    for (int rt = 0; rt < 4; ++rt) { acc2[0][rt] = fz; acc2[1][rt] = fz; }
    #pragma unroll
    for (int rt = 0; rt < 4; ++rt) {
        #pragma unroll
        for (int ks = 0; ks < 2; ++ks) {
            int row = rt * 16 + lc;
            int byte = (row * 128 + ks * 64 + lg * 16) ^ ((row & 7) << 4);
            bf16x8 a2 = *(const bf16x8*)((char*)hsm + byte);
            acc2[0][rt] = __builtin_amdgcn_mfma_f32_16x16x32_bf16(a2, b2f[0][ks], acc2[0][rt], 0, 0, 0);
            acc2[1][rt] = __builtin_amdgcn_mfma_f32_16x16x32_bf16(a2, b2f[1][ks], acc2[1][rt], 0, 0, 0);
        }
    }

    uchar* dstb = (wid < 2) ? Pb : Qb;
    #pragma unroll
    for (int t = 0; t < 2; ++t) {
        int cl = ((wid * 2 + t) * 16 + lc) & 63;
        #pragma unroll
        for (int rt = 0; rt < 4; ++rt) {
            #pragma unroll
            for (int r = 0; r < 4; ++r) {
                int node = base + rt * 16 + lg * 4 + r;
                if (node < n)
                    dstb[(size_t)node * 64 + cl] = f2fp8((acc2[t][rt][r] + bP[t]) * PQSC);
            }
        }
    }
}

// Fused MFMA edge kernel: original order + nt streaming; P/Q gathered as fp8.
__global__ __launch_bounds__(256) void k_edge2(
    const int* __restrict__ src, const int* __restrict__ dst,
    const float* __restrict__ attr,
    const uchar* __restrict__ Pb, const uchar* __restrict__ Qb,
    const ushort* __restrict__ W1cTb,
    const float* __restrict__ W2, const float* __restrict__ b2,
    float* __restrict__ out, int E) {
    __shared__ float w2s[256];
    __shared__ float b2s[4];
    w2s[threadIdx.x] = W2[threadIdx.x];
    if (threadIdx.x < 4) b2s[threadIdx.x] = b2[threadIdx.x];
    __syncthreads();

    int wid = threadIdx.x >> 6, lane = threadIdx.x & 63;
    int lg = lane >> 4, lc = lane & 15;
    int we = (blockIdx.x * 4 + wid) * 64;
    if (we >= E) return;

    int idx = we + lane; if (idx >= E) idx = E - 1;
    int sR = __builtin_nontemporal_load(src + idx);
    int dR = __builtin_nontemporal_load(dst + idx);

    // A-frags: W1cT rows rt*16+lc, k = lg*8..+7
    bf16x8 aW[4];
    #pragma unroll
    for (int rt = 0; rt < 4; ++rt)
        aW[rt] = *(const bf16x8*)(W1cTb + (rt * 16 + lc) * 32 + lg * 8);

    const f32x4 fz = {0.f, 0.f, 0.f, 0.f};
    #pragma unroll
    for (int et = 0; et < 4; ++et) {
        int erow = et * 16 + lc;
        int eid_e = we + erow; if (eid_e >= E) eid_e = E - 1;
        int s_e = __shfl(sR, erow);
        int d_e = __shfl(dR, erow);

        // B-frag: attr[eid_e][lg*8 .. +7] -> bf16 (coalesced, non-temporal)
        const f32x4* ap = (const f32x4*)(attr + (size_t)eid_e * EF + lg * 8);
        f32x4 a0 = __builtin_nontemporal_load(ap);
        f32x4 a1 = __builtin_nontemporal_load(ap + 1);
        bf16x8 bfr;
        bfr[0] = (short)f2bf(a0.x); bfr[1] = (short)f2bf(a0.y);
        bfr[2] = (short)f2bf(a0.z); bfr[3] = (short)f2bf(a0.w);
        bfr[4] = (short)f2bf(a1.x); bfr[5] = (short)f2bf(a1.y);
        bfr[6] = (short)f2bf(a1.z); bfr[7] = (short)f2bf(a1.w);

        f32x4 acc[4];
        #pragma unroll
        for (int rt = 0; rt < 4; ++rt) acc[rt] = fz;
        #pragma unroll
        for (int rt = 0; rt < 4; ++rt)
            acc[rt] = __builtin_amdgcn_mfma_f32_16x16x32_bf16(aW[rt], bfr, acc[rt], 0, 0, 0);

        const uchar* Ps = Pb + (size_t)s_e * F;
        const uchar* Qd = Qb + (size_t)d_e * F;
        float o0 = 0.f, o1 = 0.f, o2 = 0.f, o3 = 0.f;
        #pragma unroll
        for (int rt = 0; rt < 4; ++rt) {
            int j0 = rt * 16 + lg * 4;
            uint pv = *(const uint*)(Ps + j0);
            uint qv = *(const uint*)(Qd + j0);
            float p0 = __builtin_amdgcn_cvt_f32_fp8(pv, 0);
            float p1 = __builtin_amdgcn_cvt_f32_fp8(pv, 1);
            float p2 = __builtin_amdgcn_cvt_f32_fp8(pv, 2);
            float p3 = __builtin_amdgcn_cvt_f32_fp8(pv, 3);
            float q0 = __builtin_amdgcn_cvt_f32_fp8(qv, 0);
            float q1 = __builtin_amdgcn_cvt_f32_fp8(qv, 1);
            float q2 = __builtin_amdgcn_cvt_f32_fp8(qv, 2);
            float q3 = __builtin_amdgcn_cvt_f32_fp8(qv, 3);
            float h0 = fmaxf(acc[rt][0] + (p0 + q0) * PQISC, 0.f);
            float h1 = fmaxf(acc[rt][1] + (p1 + q1) * PQISC, 0.f);
            float h2 = fmaxf(acc[rt][2] + (p2 + q2) * PQISC, 0.f);
            float h3 = fmaxf(acc[rt][3] + (p3 + q3) * PQISC, 0.f);
            float4 w0 = *(const float4*)(&w2s[(j0 + 0) * 4]);
            float4 w1 = *(const float4*)(&w2s[(j0 + 1) * 4]);
            float4 w2v = *(const float4*)(&w2s[(j0 + 2) * 4]);
            float4 w3 = *(const float4*)(&w2s[(j0 + 3) * 4]);
            o0 += h0 * w0.x + h1 * w1.x + h2 * w2v.x + h3 * w3.x;
            o1 += h0 * w0.y + h1 * w1.y + h2 * w2v.y + h3 * w3.y;
            o2 += h0 * w0.z + h1 * w1.z + h2 * w2v.z + h3 * w3.z;
            o3 += h0 * w0.w + h1 * w1.w + h2 * w2v.w + h3 * w3.w;
        }
        o0 += __shfl_xor(o0, 16); o0 += __shfl_xor(o0, 32);
        o1 += __shfl_xor(o1, 16); o1 += __shfl_xor(o1, 32);
        o2 += __shfl_xor(o2, 16); o2 += __shfl_xor(o2, 32);
        o3 += __shfl_xor(o3, 16); o3 += __shfl_xor(o3, 32);
        if (lg == 0 && (we + erow) < E) {
            f32x4 ov = {o0 + b2s[0], o1 + b2s[1], o2 + b2s[2], o3 + b2s[3]};
            __builtin_nontemporal_store(ov, (f32x4*)(out + (size_t)(we + erow) * 4));
        }
    }
}

// ---------------------------------------------------------------- launch

extern "C" void kernel_launch(void* const* d_in, const int* in_sizes, int n_in,
                              void* d_out, int out_size, void* d_ws, size_t ws_size,
                              hipStream_t stream) {
    const float* x    = (const float*)d_in[0];
    const int*   ei   = (const int*)d_in[1];
    const float* attr = (const float*)d_in[2];
    const float* Wz   = (const float*)d_in[3];
    const float* bz   = (const float*)d_in[4];
    const float* Wh   = (const float*)d_in[7];
    const float* bh   = (const float*)d_in[8];
    const float* Wlz  = (const float*)d_in[9];
    const float* blz  = (const float*)d_in[10];
    const float* Wlh  = (const float*)d_in[13];
    const float* blh  = (const float*)d_in[14];
    const float* W1   = (const float*)d_in[15];
    const float* b1   = (const float*)d_in[16];
    const float* W2   = (const float*)d_in[17];
    const float* b2   = (const float*)d_in[18];
    float* out = (float*)d_out;

    const int N = in_sizes[0] / F;
    const int E = in_sizes[1] / 2;
    const int* src = ei;
    const int* dst = ei + E;
    const int NB = (N + 255) / 256;
    const int NBT = (N + 63) / 64;

    // workspace layout
    ushort* xaggb = (ushort*)d_ws;                      // N*F ushort
    uchar*  xb8   = (uchar*)(xaggb + (size_t)N * F);    // N*F uchar
    uchar*  Pb8   = xb8 + (size_t)N * F;                // N*F uchar
    uchar*  Qb8   = Pb8 + (size_t)N * F;                // N*F uchar
    ushort* B1t   = (ushort*)(Qb8 + (size_t)N * F);     // 8192
    ushort* B2t   = B1t + 8192;                         // 8192
    ushort* W1cTb = B2t + 8192;                         // 2048
    float*  V     = (float*)(W1cTb + 2048);             // 128
    int2*   es2   = (int2*)(V + 128);                   // E int2
    int*    deg   = (int*)(es2 + (size_t)E);            // N
    float*  dinv  = (float*)(deg + N);                  // N
    int*    rowptr= (int*)(dinv + N);                   // N
    int*    fill  = rowptr + N;                         // N
    int*    bsum  = fill + N;                           // <=512
    int*    boffs = bsum + 512;                         // <=512

    hipMemsetAsync(deg, 0, (size_t)N * sizeof(int), stream);
    hipMemsetAsync(fill, 0, (size_t)N * sizeof(int), stream);

    k_deg<<<(E + 255) / 256, 256, 0, stream>>>(dst, deg, E);
    k_dinv<<<NB, 256, 0, stream>>>(deg, dinv, N);
    k_weights<<<65, 64, 0, stream>>>(Wz, bz, Wh, bh, Wlz, blz, Wlh, blh, B1t, V);
    k_wcast<<<40, 256, 0, stream>>>(W1, B2t, W1cTb);
    k_xcast<<<(N * F / 8 + 255) / 256, 256, 0, stream>>>(x, xb8, N * F / 8);

    // CSR build
    k_blocksum<<<NB, 256, 0, stream>>>(deg, bsum, N);
    k_scanb<<<1, 64, 0, stream>>>(bsum, boffs, NB);
    k_rowptr<<<NB, 256, 0, stream>>>(deg, boffs, rowptr, N);
    k_bucket<<<(E + 255) / 256, 256, 0, stream>>>(src, dst, dinv, rowptr, fill, es2, E);

    k_agg<<<(N * 64 + 255) / 256, 256, 0, stream>>>(xb8, dinv, es2, rowptr, deg, xaggb, N);

    k_node<<<NBT, 256, 0, stream>>>(xaggb, B1t, B2t, V, b1, Pb8, Qb8, N);

    k_edge2<<<(E + 255) / 256, 256, 0, stream>>>(src, dst, attr, Pb8, Qb8, W1cTb, W2, b2, out, E);
}